// Round 3
// baseline (1171.600 us; speedup 1.0000x reference)
//
#include <hip/hip_runtime.h>
#include <math.h>

// Problem constants (from reference)
#define NPTS     16384
#define KNN_K    40
#define KNN_CAPW 320   // per (wave,row) survivor segment (u32 keys)

typedef unsigned short u16;
typedef __attribute__((ext_vector_type(8))) short bf16x8;
typedef __attribute__((ext_vector_type(4))) float f32x4;

// ---- bf16 (stored as ushort bits) helpers: fp32 compute, bf16 storage -----
static __device__ __forceinline__ float bf2f(unsigned short h) {
  return __uint_as_float(((unsigned)h) << 16);
}
static __device__ __forceinline__ unsigned short f2bf(float f) {
  unsigned u = __float_as_uint(f);
  unsigned r = (u + 0x7fffu + ((u >> 16) & 1u)) >> 16;   // round-nearest-even
  return (unsigned short)r;
}
static __device__ __forceinline__ float ldf(const float* p) { return *p; }
static __device__ __forceinline__ float ldf(const unsigned short* p) { return bf2f(*p); }

static __device__ __forceinline__ float rfl(float x) {   // readfirstlane -> SGPR
  return __uint_as_float(__builtin_amdgcn_readfirstlane(__float_as_uint(x)));
}
static __device__ __forceinline__ unsigned mbcnt64(unsigned long long m) {
  return __builtin_amdgcn_mbcnt_hi((unsigned)(m >> 32),
                                   __builtin_amdgcn_mbcnt_lo((unsigned)m, 0u));
}

// monotone float<->uint encoding for atomic min/max
static __device__ __forceinline__ unsigned encf(float f) {
  unsigned b = __float_as_uint(f);
  return (b & 0x80000000u) ? ~b : (b | 0x80000000u);
}
static __device__ __forceinline__ float decf(unsigned e) {
  unsigned b = (e & 0x80000000u) ? (e ^ 0x80000000u) : ~e;
  return __uint_as_float(b);
}

// ---------------------------------------------------------------------------
// MFMA GEMM: C[N x MCOLS] = (relu?)(concat(A1,A2) @ W + bias), bf16 in/out,
// fp32 weights split hi/lo bf16 -> two chained MFMAs.
// ---------------------------------------------------------------------------
template<int MCOLS, bool RELU>
__global__ __launch_bounds__(256, 2) void gemm_mfma_k(
    const u16* __restrict__ A1, int lda1,
    const u16* __restrict__ A2, int lda2, int K1,
    const float* __restrict__ W, const float* __restrict__ bias,
    u16* __restrict__ C, int ldc, int K)
{
  constexpr int CT = MCOLS / 64;
  constexpr int AST = 40;
  __shared__ u16 lds[64 * AST + 2 * MCOLS * AST];
  u16* As = lds;
  u16* Wh = lds + 64 * AST;
  u16* Wl = Wh + MCOLS * AST;

  const int tid = threadIdx.x;
  const int lane = tid & 63;
  const int w = tid >> 6;
  const int row0 = blockIdx.x * 64;

  f32x4 acc[4][CT];
  #pragma unroll
  for (int rt = 0; rt < 4; ++rt)
    #pragma unroll
    for (int ct = 0; ct < CT; ++ct)
      acc[rt][ct] = (f32x4){0.f, 0.f, 0.f, 0.f};

  const int rbase = lane & 15;
  const int koff = (lane >> 4) * 8;

  for (int k0 = 0; k0 < K; k0 += 32) {
    __syncthreads();
    {
      int r = tid >> 2, seg = tid & 3;
      int kk = k0 + seg * 8;
      const u16* src = (kk < K1) ? &A1[(size_t)(row0 + r) * lda1 + kk]
                                 : &A2[(size_t)(row0 + r) * lda2 + (kk - K1)];
      *(uint4*)&As[r * AST + seg * 8] = *(const uint4*)src;
    }
    for (int l = tid; l < 32 * MCOLS; l += 256) {
      int n = l & (MCOLS - 1), kk = l / MCOLS;
      float wv = W[(size_t)(k0 + kk) * MCOLS + n];
      u16 h = f2bf(wv);
      Wh[n * AST + kk] = h;
      Wl[n * AST + kk] = f2bf(wv - bf2f(h));
    }
    __syncthreads();

    bf16x8 a[4];
    #pragma unroll
    for (int rt = 0; rt < 4; ++rt)
      a[rt] = *(const bf16x8*)&As[(rt * 16 + rbase) * AST + koff];
    #pragma unroll
    for (int ct = 0; ct < CT; ++ct) {
      int col = (w * CT + ct) * 16 + rbase;
      bf16x8 bh = *(const bf16x8*)&Wh[col * AST + koff];
      bf16x8 bl = *(const bf16x8*)&Wl[col * AST + koff];
      #pragma unroll
      for (int rt = 0; rt < 4; ++rt) {
        acc[rt][ct] = __builtin_amdgcn_mfma_f32_16x16x32_bf16(a[rt], bh, acc[rt][ct], 0, 0, 0);
        acc[rt][ct] = __builtin_amdgcn_mfma_f32_16x16x32_bf16(a[rt], bl, acc[rt][ct], 0, 0, 0);
      }
    }
  }

  __syncthreads();
  constexpr int CST = MCOLS + 8;
  u16* Ct = lds;
  const int rq = (lane >> 4) * 4;
  #pragma unroll
  for (int ct = 0; ct < CT; ++ct) {
    int col = (w * CT + ct) * 16 + rbase;
    float bv = bias[col];
    #pragma unroll
    for (int rt = 0; rt < 4; ++rt) {
      #pragma unroll
      for (int q = 0; q < 4; ++q) {
        float v = acc[rt][ct][q] + bv;
        if (RELU) v = fmaxf(v, 0.f);
        Ct[(rt * 16 + rq + q) * CST + col] = f2bf(v);
      }
    }
  }
  __syncthreads();
  constexpr int SEGS = MCOLS / 8;
  for (int l = tid; l < 64 * SEGS; l += 256) {
    int r = l / SEGS, sg = l % SEGS;
    *(uint4*)&C[(size_t)(row0 + r) * ldc + sg * 8] = *(const uint4*)&Ct[r * CST + sg * 8];
  }
}

// ---------------------------------------------------------------------------
// VALU GEMM (fc1 only: K=9, fp32 input)
// ---------------------------------------------------------------------------
template<int MCOLS, bool RELU, typename TIN, typename TOUT>
__global__ __launch_bounds__(256, 4) void gemm_k(
    const TIN* __restrict__ A1, int lda1,
    const TIN* __restrict__ A2, int lda2, int K1,
    const float* __restrict__ W, const float* __restrict__ bias,
    TOUT* __restrict__ C, int ldc, int K)
{
  constexpr int TCS = MCOLS / 8;
  constexpr int RPT = (64 * TCS) / 256;
  __shared__ float Asl[64][33];
  __shared__ float Ws[32][MCOLS];
  const int tid = threadIdx.x;
  const int row0 = blockIdx.x * 64;
  const int tc = tid % TCS, tr = tid / TCS;

  float acc[RPT][8];
  #pragma unroll
  for (int p = 0; p < RPT; ++p)
    #pragma unroll
    for (int q = 0; q < 8; ++q) acc[p][q] = 0.f;

  for (int k0 = 0; k0 < K; k0 += 32) {
    __syncthreads();
    for (int l = tid; l < 64 * 32; l += 256) {
      int r = l >> 5, c = l & 31, k = k0 + c;
      float v = 0.f;
      if (k < K) v = (k < K1) ? ldf(&A1[(size_t)(row0 + r) * lda1 + k])
                              : ldf(&A2[(size_t)(row0 + r) * lda2 + (k - K1)]);
      Asl[r][c] = v;
    }
    for (int l = tid; l < 32 * MCOLS; l += 256) {
      int kr = l / MCOLS, c = l % MCOLS, k = k0 + kr;
      Ws[kr][c] = (k < K) ? W[(size_t)k * MCOLS + c] : 0.f;
    }
    __syncthreads();
    #pragma unroll
    for (int kk = 0; kk < 32; ++kk) {
      float a[RPT];
      #pragma unroll
      for (int p = 0; p < RPT; ++p) a[p] = Asl[tr * RPT + p][kk];
      const float4 w0 = *(const float4*)&Ws[kk][tc * 8];
      const float4 w1 = *(const float4*)&Ws[kk][tc * 8 + 4];
      #pragma unroll
      for (int p = 0; p < RPT; ++p) {
        acc[p][0] = fmaf(a[p], w0.x, acc[p][0]);
        acc[p][1] = fmaf(a[p], w0.y, acc[p][1]);
        acc[p][2] = fmaf(a[p], w0.z, acc[p][2]);
        acc[p][3] = fmaf(a[p], w0.w, acc[p][3]);
        acc[p][4] = fmaf(a[p], w1.x, acc[p][4]);
        acc[p][5] = fmaf(a[p], w1.y, acc[p][5]);
        acc[p][6] = fmaf(a[p], w1.z, acc[p][6]);
        acc[p][7] = fmaf(a[p], w1.w, acc[p][7]);
      }
    }
  }

  const float4 b0 = *(const float4*)&bias[tc * 8];
  const float4 b1 = *(const float4*)&bias[tc * 8 + 4];
  #pragma unroll
  for (int p = 0; p < RPT; ++p) {
    int r = row0 + tr * RPT + p;
    float o[8];
    o[0] = acc[p][0] + b0.x; o[1] = acc[p][1] + b0.y;
    o[2] = acc[p][2] + b0.z; o[3] = acc[p][3] + b0.w;
    o[4] = acc[p][4] + b1.x; o[5] = acc[p][5] + b1.y;
    o[6] = acc[p][6] + b1.z; o[7] = acc[p][7] + b1.w;
    if (RELU) {
      #pragma unroll
      for (int q = 0; q < 8; ++q) o[q] = fmaxf(o[q], 0.f);
    }
    if constexpr (sizeof(TOUT) == 2) {
      unsigned p0 = (unsigned)f2bf(o[0]) | ((unsigned)f2bf(o[1]) << 16);
      unsigned p1 = (unsigned)f2bf(o[2]) | ((unsigned)f2bf(o[3]) << 16);
      unsigned p2 = (unsigned)f2bf(o[4]) | ((unsigned)f2bf(o[5]) << 16);
      unsigned p3 = (unsigned)f2bf(o[6]) | ((unsigned)f2bf(o[7]) << 16);
      uint4 pk = make_uint4(p0, p1, p2, p3);
      *(uint4*)&C[(size_t)r * ldc + tc * 8] = pk;
    } else {
      float4 o0, o1;
      o0.x = o[0]; o0.y = o[1]; o0.z = o[2]; o0.w = o[3];
      o1.x = o[4]; o1.y = o[5]; o1.z = o[6]; o1.w = o[7];
      *(float4*)&C[(size_t)r * ldc + tc * 8] = o0;
      *(float4*)&C[(size_t)r * ldc + tc * 8 + 4] = o1;
    }
  }
}

// ---------------------------------------------------------------------------
// Small-M GEMM (M = 4): lin_s (MM=true fuses per-dim min/max atomics) and fc4.
// ---------------------------------------------------------------------------
template<bool RELU, bool MM, typename TOUT>
__global__ __launch_bounds__(256, 4) void gemm4_k(
    const u16* __restrict__ A, int lda,
    const float* __restrict__ W, const float* __restrict__ bias,
    TOUT* __restrict__ C, int K, unsigned* mm)
{
  __shared__ float Wsl[128 * 4];
  __shared__ float bl[4];
  const int tid = threadIdx.x;
  for (int l = tid; l < K * 4; l += 256) Wsl[l] = W[l];
  if (tid < 4) bl[tid] = bias[tid];
  __syncthreads();
  const int row = blockIdx.x * 256 + tid;
  const u16* ap = A + (size_t)row * lda;
  float a0 = bl[0], a1 = bl[1], a2 = bl[2], a3 = bl[3];
  for (int k8 = 0; k8 < K; k8 += 8) {
    uint4 pk = *(const uint4*)&ap[k8];
    unsigned uu[4] = {pk.x, pk.y, pk.z, pk.w};
    #pragma unroll
    for (int q = 0; q < 4; ++q) {
      float flo = __uint_as_float(uu[q] << 16);
      float fhi = __uint_as_float(uu[q] & 0xFFFF0000u);
      const float* wr0 = &Wsl[(k8 + 2 * q) * 4];
      a0 = fmaf(flo, wr0[0], a0); a1 = fmaf(flo, wr0[1], a1);
      a2 = fmaf(flo, wr0[2], a2); a3 = fmaf(flo, wr0[3], a3);
      a0 = fmaf(fhi, wr0[4], a0); a1 = fmaf(fhi, wr0[5], a1);
      a2 = fmaf(fhi, wr0[6], a2); a3 = fmaf(fhi, wr0[7], a3);
    }
  }
  if (RELU) {
    a0 = fmaxf(a0, 0.f); a1 = fmaxf(a1, 0.f);
    a2 = fmaxf(a2, 0.f); a3 = fmaxf(a3, 0.f);
  }
  if constexpr (sizeof(TOUT) == 2) {
    C[(size_t)row * 4 + 0] = (TOUT)f2bf(a0);
    C[(size_t)row * 4 + 1] = (TOUT)f2bf(a1);
    C[(size_t)row * 4 + 2] = (TOUT)f2bf(a2);
    C[(size_t)row * 4 + 3] = (TOUT)f2bf(a3);
  } else {
    float4 o; o.x = a0; o.y = a1; o.z = a2; o.w = a3;
    *(float4*)&C[(size_t)row * 4] = o;
  }
  if constexpr (MM) {
    float mn0 = a0, mx0 = a0, mn1 = a1, mx1 = a1;
    float mn2 = a2, mx2 = a2, mn3 = a3, mx3 = a3;
    #pragma unroll
    for (int o = 32; o >= 1; o >>= 1) {
      mn0 = fminf(mn0, __shfl_xor(mn0, o, 64)); mx0 = fmaxf(mx0, __shfl_xor(mx0, o, 64));
      mn1 = fminf(mn1, __shfl_xor(mn1, o, 64)); mx1 = fmaxf(mx1, __shfl_xor(mx1, o, 64));
      mn2 = fminf(mn2, __shfl_xor(mn2, o, 64)); mx2 = fmaxf(mx2, __shfl_xor(mx2, o, 64));
      mn3 = fminf(mn3, __shfl_xor(mn3, o, 64)); mx3 = fmaxf(mx3, __shfl_xor(mx3, o, 64));
    }
    if ((tid & 63) == 0) {
      atomicMin(&mm[0], encf(mn0)); atomicMax(&mm[4], encf(mx0));
      atomicMin(&mm[1], encf(mn1)); atomicMax(&mm[5], encf(mx1));
      atomicMin(&mm[2], encf(mn2)); atomicMax(&mm[6], encf(mx2));
      atomicMin(&mm[3], encf(mn3)); atomicMax(&mm[7], encf(mx3));
    }
  }
}

// ---------------------------------------------------------------------------
// Cell-sort prep: init mm -> (gemm4 fills min/max) -> histpref (1 block:
// picks 2 widest dims, 16x16 hist, prefix) -> scatter -> per-group AABBs.
// ---------------------------------------------------------------------------
__global__ void init_mm_k(unsigned* mm) {
  int t = threadIdx.x;
  if (t < 4) { mm[t] = 0xFFFFFFFFu; mm[4 + t] = 0u; }
}

static __device__ __forceinline__ float dimsel(float4 p, int d) {
  return (d == 0) ? p.x : (d == 1) ? p.y : (d == 2) ? p.z : p.w;
}

__global__ __launch_bounds__(1024, 1) void histpref_k(
    const float* __restrict__ S, unsigned* __restrict__ mm,
    unsigned* __restrict__ binoff)
{
  __shared__ unsigned hist[256];
  __shared__ unsigned wsum[4];
  const int tid = threadIdx.x;
  float mn[4], rg[4];
  #pragma unroll
  for (int d = 0; d < 4; ++d) {
    mn[d] = decf(mm[d]);
    rg[d] = decf(mm[4 + d]) - mn[d];
  }
  int a = 0;
  #pragma unroll
  for (int d = 1; d < 4; ++d) if (rg[d] > rg[a]) a = d;
  int b = (a == 0) ? 1 : 0;
  #pragma unroll
  for (int d = 0; d < 4; ++d) if (d != a && rg[d] > rg[b]) b = d;
  float inva = (rg[a] > 0.f) ? (16.f / rg[a]) * 0.999999f : 0.f;
  float invb = (rg[b] > 0.f) ? (16.f / rg[b]) * 0.999999f : 0.f;
  if (tid == 0) {
    mm[8] = (unsigned)a; mm[9] = (unsigned)b;
    mm[10] = __float_as_uint(mn[a]); mm[11] = __float_as_uint(inva);
    mm[12] = __float_as_uint(mn[b]); mm[13] = __float_as_uint(invb);
  }
  if (tid < 256) hist[tid] = 0u;
  __syncthreads();
  for (int i = tid; i < NPTS; i += 1024) {
    float4 p = *(const float4*)&S[(size_t)i * 4];
    int ba = min(15, max(0, (int)((dimsel(p, a) - mn[a]) * inva)));
    int bb = min(15, max(0, (int)((dimsel(p, b) - mn[b]) * invb)));
    atomicAdd(&hist[ba * 16 + bb], 1u);
  }
  __syncthreads();
  unsigned v = 0, x = 0;
  if (tid < 256) {
    int lane = tid & 63;
    v = hist[tid]; x = v;
    #pragma unroll
    for (int o = 1; o < 64; o <<= 1) {
      unsigned t = (unsigned)__shfl_up((int)x, o, 64);
      if (lane >= o) x += t;
    }
    if (lane == 63) wsum[tid >> 6] = x;
  }
  __syncthreads();
  if (tid < 256) {
    unsigned off = 0;
    for (int k = 0; k < (tid >> 6); ++k) off += wsum[k];
    binoff[tid] = off + x - v;   // exclusive prefix
  }
}

__global__ __launch_bounds__(256, 4) void scatter_k(
    const float* __restrict__ S, const unsigned* __restrict__ mm,
    unsigned* __restrict__ binoff,
    float4* __restrict__ SX4, float* __restrict__ SS2, u16* __restrict__ SIDXs)
{
  int a = (int)mm[8], b = (int)mm[9];
  float alo = __uint_as_float(mm[10]), inva = __uint_as_float(mm[11]);
  float blo = __uint_as_float(mm[12]), invb = __uint_as_float(mm[13]);
  int i = blockIdx.x * 256 + threadIdx.x;
  float4 p = *(const float4*)&S[(size_t)i * 4];
  int ba = min(15, max(0, (int)((dimsel(p, a) - alo) * inva)));
  int bb = min(15, max(0, (int)((dimsel(p, b) - blo) * invb)));
  unsigned pos = atomicAdd(&binoff[ba * 16 + bb], 1u);
  SX4[pos] = p;
  SS2[pos] = fmaf(p.x, p.x, fmaf(p.y, p.y, fmaf(p.z, p.z, p.w * p.w)));
  SIDXs[pos] = (u16)i;
}

__global__ __launch_bounds__(512, 4) void gaabb_k(const float4* __restrict__ SX4,
                                                  float* __restrict__ gaabb) {
  int w = threadIdx.x >> 6, lane = threadIdx.x & 63;
  int g = blockIdx.x * 8 + w;
  float4 p = SX4[g * 64 + lane];
  float mnx = p.x, mny = p.y, mnz = p.z, mnw = p.w;
  float mxx = p.x, mxy = p.y, mxz = p.z, mxw = p.w;
  #pragma unroll
  for (int o = 32; o >= 1; o >>= 1) {
    mnx = fminf(mnx, __shfl_xor(mnx, o, 64)); mxx = fmaxf(mxx, __shfl_xor(mxx, o, 64));
    mny = fminf(mny, __shfl_xor(mny, o, 64)); mxy = fmaxf(mxy, __shfl_xor(mxy, o, 64));
    mnz = fminf(mnz, __shfl_xor(mnz, o, 64)); mxz = fmaxf(mxz, __shfl_xor(mxz, o, 64));
    mnw = fminf(mnw, __shfl_xor(mnw, o, 64)); mxw = fmaxf(mxw, __shfl_xor(mxw, o, 64));
  }
  if (lane == 0) {
    float4* gp = (float4*)&gaabb[g * 8];
    gp[0] = make_float4(mnx, mny, mnz, mnw);
    gp[1] = make_float4(mxx, mxy, mxz, mxw);
  }
}

// ---------------------------------------------------------------------------
// kNN v10: v9 + (a) occupancy 4->6 blocks/CU (LDS 23.5KB allows 6; VGPR tiny)
// to shorten the finish-skew tail, (b) depth-2 register prefetch pipeline in
// the walk so ~2 groups of compute cover the L2 load latency.
// ---------------------------------------------------------------------------
struct CompactRes { int cnt; unsigned thr; };

static __device__ __forceinline__ CompactRes compact_buf(unsigned* bufR, int cnt, int lane) {
  int n = min(cnt, KNN_CAPW);
  int lo = -1, hi = 0x7FFFFFFF, chi = n;
  for (int it = 0; it < 32; ++it) {
    if (chi <= 96) break;
    int mid = lo + ((hi - lo) >> 1);
    int lc = 0;
    for (int base = 0; base < n; base += 64) {
      int i = base + lane;
      bool c = (i < n) && (bufR[i] <= (unsigned)mid);
      lc += (int)__popcll(__ballot(c));
    }
    if (lc >= 40) { hi = mid; chi = lc; } else lo = mid;
  }
  unsigned thr = (unsigned)hi;
  int out = 0;
  for (int base = 0; base < n; base += 64) {
    int i = base + lane;
    unsigned key = (i < n) ? bufR[i] : 0xFFFFFFFFu;
    bool keep = (i < n) && (key <= thr);
    unsigned long long mk = __ballot(keep);
    unsigned pre = mbcnt64(mk);
    if (keep) bufR[out + (int)pre] = key;
    out += (int)__popcll(mk);
  }
  CompactRes r; r.cnt = out; r.thr = thr;
  return r;
}

__global__ __launch_bounds__(256, 6) void knn_k(
    const float4* __restrict__ SX4, const float* __restrict__ SS2,
    const u16* __restrict__ SIDXs, const float* __restrict__ gaabb,
    u16* __restrict__ idx_out, u16* __restrict__ w_out)
{
  __shared__ unsigned buf[4 * 4 * KNN_CAPW];   // 20 KB; phase-1 min2 aliases it
  __shared__ unsigned scr[4 * 128];            // 2 KB: per-row merge scratch
  __shared__ int cnts[16];                     // [wave][row]
  __shared__ unsigned thrend[16];              // [wave][row] final thr keys
  __shared__ unsigned short glist[4 * 64];     // per-wave surviving-group list
  __shared__ unsigned long long mws[4];        // group mask, 64 groups per wave
  __shared__ unsigned thrsh[4];                // per-row thr0 (uint float bits)

  const int tid = threadIdx.x;
  const int lane = tid & 63;
  const int w = tid >> 6;
  const int sp0 = blockIdx.x * 4;              // 4 rows per block, shared

  float cx[4], cy[4], cz[4], cw[4], s2r[4], thrF[4];
  int orow[4], cnt[4];
  #pragma unroll
  for (int r = 0; r < 4; ++r) {
    float4 sr = SX4[sp0 + r];
    cx[r] = rfl(-2.f * sr.x); cy[r] = rfl(-2.f * sr.y);
    cz[r] = rfl(-2.f * sr.z); cw[r] = rfl(-2.f * sr.w);
    s2r[r] = rfl(fmaf(sr.x, sr.x, fmaf(sr.y, sr.y, fmaf(sr.z, sr.z, sr.w * sr.w))));
    orow[r] = SIDXs[sp0 + r];
    cnt[r] = 0;
  }
  unsigned* bufw = &buf[w * 4 * KNN_CAPW];
  unsigned* mph = buf;   // phase-1 min2 exchange: [(r*8 + w*2+h)*64 + lane]

  // ---- phase 1 (split): wave w scans 4 of the 16 window groups ----
  {
    int gs = sp0 >> 6;
    int g0 = min(max(gs - 7, 0), 240);
    float m1[4], m2[4];
    #pragma unroll
    for (int r = 0; r < 4; ++r) { m1[r] = 3.0e38f; m2[r] = 3.0e38f; }
    #pragma unroll
    for (int gi = 0; gi < 4; ++gi) {
      int j = (g0 + w * 4 + gi) * 64 + lane;
      float4 p = SX4[j];
      float q = SS2[j];
      #pragma unroll
      for (int r = 0; r < 4; ++r) {
        float d = fmaf(cx[r], p.x, fmaf(cy[r], p.y, fmaf(cz[r], p.z,
                  fmaf(cw[r], p.w, q + s2r[r]))));
        d = fmaxf(d, 0.f);
        bool lt1 = d < m1[r];
        float nm2 = lt1 ? m1[r] : fminf(m2[r], d);
        m1[r] = fminf(m1[r], d);
        m2[r] = nm2;
      }
    }
    #pragma unroll
    for (int r = 0; r < 4; ++r) {
      mph[(r * 8 + w * 2 + 0) * 64 + lane] = __float_as_uint(m1[r]);
      mph[(r * 8 + w * 2 + 1) * 64 + lane] = __float_as_uint(m2[r]);
    }
  }
  __syncthreads();

  // ---- thr0: wave w bisects row w over the 512-value union ----
  {
    unsigned vals[8];
    #pragma unroll
    for (int s = 0; s < 8; ++s) vals[s] = mph[(w * 8 + s) * 64 + lane];
    int lo = -1, hi = 0x7F800000, chi = 512;
    for (int it = 0; it < 32; ++it) {
      if (chi <= 44 || (hi - lo) <= 1) break;
      int mid = lo + ((hi - lo) >> 1);
      int c = 0;
      #pragma unroll
      for (int s = 0; s < 8; ++s)
        c += (int)__popcll(__ballot(vals[s] <= (unsigned)mid));
      if (c >= 40) { hi = mid; chi = c; } else lo = mid;
    }
    if (lane == 0) thrsh[w] = (unsigned)hi;
  }
  __syncthreads();
  #pragma unroll
  for (int r = 0; r < 4; ++r) thrF[r] = __uint_as_float(thrsh[r]);

  // ---- group mask (split): wave w tests groups [w*64, w*64+64) ----
  {
    int g = w * 64 + lane;
    float4 mn = *(const float4*)&gaabb[g * 8];
    float4 mx = *(const float4*)&gaabb[g * 8 + 4];
    bool want = false;
    #pragma unroll
    for (int r = 0; r < 4; ++r) {
      float px = -0.5f * cx[r], py = -0.5f * cy[r];
      float pz = -0.5f * cz[r], pw = -0.5f * cw[r];
      float dx = fmaxf(fmaxf(mn.x - px, px - mx.x), 0.f);
      float dy = fmaxf(fmaxf(mn.y - py, py - mx.y), 0.f);
      float dz = fmaxf(fmaxf(mn.z - pz, pz - mx.z), 0.f);
      float dw = fmaxf(fmaxf(mn.w - pw, pw - mx.w), 0.f);
      float md = fmaf(dx, dx, fmaf(dy, dy, fmaf(dz, dz, dw * dw)));
      want |= (md <= thrF[r]);
    }
    unsigned long long bal = __ballot(want);
    if (lane == 0) mws[w] = bal;
  }
  __syncthreads();

  // ---- glist (parallel): survivors with ordinal%4 == w, via ballot-prefix --
  int ng = 0;
  {
    int ordbase = 0;
    #pragma unroll
    for (int pgi = 0; pgi < 4; ++pgi) {
      unsigned long long m = mws[pgi];
      bool want = (m >> lane) & 1ull;
      int ord = ordbase + (int)mbcnt64(m);
      if (want && ((ord & 3) == w))
        glist[w * 64 + (ord >> 2)] = (unsigned short)(pgi * 64 + lane);
      ordbase += (int)__popcll(m);
    }
    ng = (ordbase + 3 - w) >> 2;
  }

  // ---- phase 2: walk my groups, depth-2 register prefetch pipeline ----
  if (ng > 0) {
    int jA = (int)glist[w * 64] * 64 + lane;
    float4 pA = SX4[jA]; float qA = SS2[jA]; unsigned svA = (unsigned)jA;
    float4 pB = pA; float qB = qA; unsigned svB = svA;
    if (ng > 1) {
      int jB = (int)glist[w * 64 + 1] * 64 + lane;
      pB = SX4[jB]; qB = SS2[jB]; svB = (unsigned)jB;
    }
    for (int i = 0; i < ng; ++i) {
      float4 pC = pA; float qC = qA; unsigned svC = svA;
      if (i + 2 < ng) {
        int jC = (int)glist[w * 64 + i + 2] * 64 + lane;
        pC = SX4[jC]; qC = SS2[jC]; svC = (unsigned)jC;
      }
      #pragma unroll
      for (int r = 0; r < 4; ++r) {
        float d = fmaf(cx[r], pA.x, fmaf(cy[r], pA.y, fmaf(cz[r], pA.z,
                  fmaf(cw[r], pA.w, qA + s2r[r]))));
        bool k = d <= thrF[r];
        unsigned long long mk = __ballot(k);
        if (mk) {
          int pos = cnt[r] + (int)mbcnt64(mk);
          if (k) bufw[r * KNN_CAPW + pos] =
              (__float_as_uint(fmaxf(d, 0.f)) & 0xFFFFC000u) | svA;
          cnt[r] += (int)__popcll(mk);
          if (cnt[r] >= KNN_CAPW - 64) {   // pre-group cnt <= 255 -> no overflow
            CompactRes cr = compact_buf(&bufw[r * KNN_CAPW], cnt[r], lane);
            cnt[r] = cr.cnt;
            thrF[r] = __uint_as_float((cr.thr & 0xFFFFC000u) | 0x3FFFu);
          }
        }
      }
      pA = pB; qA = qB; svA = svB;
      pB = pC; qB = qC; svB = svC;
    }
  }

  if (lane == 0) {
    #pragma unroll
    for (int r = 0; r < 4; ++r) {
      cnts[w * 4 + r] = cnt[r];
      thrend[w * 4 + r] = (__float_as_uint(thrF[r]) & 0xFFFFC000u) | 0x3FFFu;
    }
  }
  __syncthreads();

  // ---- merge + finalists: wave w owns row w ----
  {
    const int rr = w;
    const unsigned* seg[4];
    int c[4], off[5];
    off[0] = 0;
    #pragma unroll
    for (int s = 0; s < 4; ++s) {
      seg[s] = &buf[(s * 4 + rr) * KNN_CAPW];
      c[s] = cnts[s * 4 + rr];
      off[s + 1] = off[s] + c[s];
    }
    int mt = off[4];
    unsigned* S = &scr[rr * 128];

    if (mt > 128) {
      // hi0 = min over waves of final thr keys: valid global threshold
      unsigned hi0 = min(min(thrend[0 * 4 + rr], thrend[1 * 4 + rr]),
                         min(thrend[2 * 4 + rr], thrend[3 * 4 + rr]));
      int lc = 0;
      #pragma unroll
      for (int s = 0; s < 4; ++s)
        for (int base = 0; base < c[s]; base += 64) {
          int i = base + lane;
          bool cc = (i < c[s]) && (seg[s][i] <= hi0);
          lc += (int)__popcll(__ballot(cc));
        }
      unsigned thrm = hi0;
      if (lc > 128) {
        int lo = -1, hi = (int)hi0, chi = lc;
        for (int it = 0; it < 32; ++it) {
          if (chi <= 96) break;
          int mid = lo + ((hi - lo) >> 1);
          int lc2 = 0;
          #pragma unroll
          for (int s = 0; s < 4; ++s)
            for (int base = 0; base < c[s]; base += 64) {
              int i = base + lane;
              bool cc = (i < c[s]) && (seg[s][i] <= (unsigned)mid);
              lc2 += (int)__popcll(__ballot(cc));
            }
          if (lc2 >= 40) { hi = mid; chi = lc2; } else lo = mid;
        }
        thrm = (unsigned)hi;
      }
      int out = 0;
      #pragma unroll
      for (int s = 0; s < 4; ++s)
        for (int base = 0; base < c[s]; base += 64) {
          int i = base + lane;
          unsigned key = (i < c[s]) ? seg[s][i] : 0xFFFFFFFFu;
          bool keep = (i < c[s]) && (key <= thrm);
          unsigned long long mk = __ballot(keep);
          int pos = out + (int)mbcnt64(mk);
          if (keep && pos < 128) S[pos] = key;
          out += (int)__popcll(mk);
        }
      mt = min(out, 128);
    } else {
      #pragma unroll
      for (int s = 0; s < 4; ++s)
        for (int base = 0; base < c[s]; base += 64) {
          int i = base + lane;
          if (i < c[s]) S[off[s] + i] = seg[s][i];
        }
    }

    // exact d2 recompute + bitonic-128 sort + emit top-40
    const float fx = cx[rr], fy = cy[rr], fz = cz[rr], fw = cw[rr];
    const float s2i = s2r[rr];
    const int row = orow[rr];

    unsigned long long e0 = ~0ull, e1 = ~0ull;
    {
      int sl0 = lane * 2, sl1 = lane * 2 + 1;
      if (sl0 < mt) {
        unsigned key = S[sl0];
        unsigned sj = key & 0x3FFFu;
        float4 p = SX4[sj];
        float qj = fmaf(p.x, p.x, fmaf(p.y, p.y, fmaf(p.z, p.z, p.w * p.w)));
        float d = fmaf(fx, p.x, fmaf(fy, p.y, fmaf(fz, p.z, fmaf(fw, p.w, qj + s2i))));
        unsigned oi = (unsigned)SIDXs[sj];
        e0 = (((unsigned long long)__float_as_uint(fmaxf(d, 0.f))) << 32) | oi;
      }
      if (sl1 < mt) {
        unsigned key = S[sl1];
        unsigned sj = key & 0x3FFFu;
        float4 p = SX4[sj];
        float qj = fmaf(p.x, p.x, fmaf(p.y, p.y, fmaf(p.z, p.z, p.w * p.w)));
        float d = fmaf(fx, p.x, fmaf(fy, p.y, fmaf(fz, p.z, fmaf(fw, p.w, qj + s2i))));
        unsigned oi = (unsigned)SIDXs[sj];
        e1 = (((unsigned long long)__float_as_uint(fmaxf(d, 0.f))) << 32) | oi;
      }
    }

    #pragma unroll
    for (int k = 2; k <= 128; k <<= 1) {
      #pragma unroll
      for (int jj = k >> 1; jj >= 1; jj >>= 1) {
        bool up = (((lane * 2) & k) == 0);
        if (jj == 1) {
          unsigned long long a = (e0 < e1) ? e0 : e1;
          unsigned long long b = (e0 < e1) ? e1 : e0;
          e0 = up ? a : b; e1 = up ? b : a;
        } else {
          int lj = jj >> 1;
          bool lower = ((lane & lj) == 0);
          bool tm = (up == lower);
          unsigned long long o0 = __shfl_xor(e0, lj, 64);
          e0 = tm ? ((e0 < o0) ? e0 : o0) : ((e0 > o0) ? e0 : o0);
          unsigned long long o1 = __shfl_xor(e1, lj, 64);
          e1 = tm ? ((e1 < o1) ? e1 : o1) : ((e1 > o1) ? e1 : o1);
        }
      }
    }

    const int ob = row * KNN_K;
    if (lane < 20) {
      int v0 = lane * 2;
      idx_out[ob + v0] = (unsigned short)(e0 & 0xFFFFu);
      w_out[ob + v0] = f2bf(__expf(-10.f * __uint_as_float((unsigned)(e0 >> 32))));
      int v1 = v0 + 1;
      idx_out[ob + v1] = (unsigned short)(e1 & 0xFFFFu);
      w_out[ob + v1] = f2bf(__expf(-10.f * __uint_as_float((unsigned)(e1 >> 32))));
    }
  }
}

// ---------------------------------------------------------------------------
// Aggregation: Aout[i] = [mean_k h[idx]*w | max_k h[idx]*w]  (N x 128, bf16).
// ---------------------------------------------------------------------------
__global__ __launch_bounds__(256, 4) void agg_k(
    const unsigned short* __restrict__ h, const unsigned short* __restrict__ idxb,
    const unsigned short* __restrict__ wb, unsigned short* __restrict__ Aout)
{
  const int row = blockIdx.x * 4 + (threadIdx.x >> 6);
  const int lane = threadIdx.x & 63;
  const int base = row * KNN_K;
  float mean = 0.f, mx = -INFINITY;
  #pragma unroll 4
  for (int k = 0; k < KNN_K; ++k) {
    int j = idxb[base + k];
    float wv = bf2f(wb[base + k]);
    float m = bf2f(h[(size_t)j * 64 + lane]) * wv;
    mean += m;
    mx = fmaxf(mx, m);
  }
  Aout[(size_t)row * 128 + lane] = f2bf(mean * (1.f / 40.f));
  Aout[(size_t)row * 128 + 64 + lane] = f2bf(mx);
}

// ---------------------------------------------------------------------------
extern "C" void kernel_launch(void* const* d_in, const int* in_sizes, int n_in,
                              void* d_out, int out_size, void* d_ws, size_t ws_size,
                              hipStream_t stream)
{
  const float* x    = (const float*)d_in[0];
  const float* fc1W = (const float*)d_in[1];  const float* fc1b = (const float*)d_in[2];
  const float* fc2W = (const float*)d_in[3];  const float* fc2b = (const float*)d_in[4];
  const float* gsW  = (const float*)d_in[5];  const float* gsb  = (const float*)d_in[6];
  const float* ghW  = (const float*)d_in[7];  const float* ghb  = (const float*)d_in[8];
  const float* goW  = (const float*)d_in[9];  const float* gob  = (const float*)d_in[10];
  const float* d1W  = (const float*)d_in[11]; const float* d1b  = (const float*)d_in[12];
  const float* d2W  = (const float*)d_in[13]; const float* d2b  = (const float*)d_in[14];
  const float* d3W  = (const float*)d_in[15]; const float* d3b  = (const float*)d_in[16];
  const float* fc3W = (const float*)d_in[17]; const float* fc3b = (const float*)d_in[18];
  const float* fc4W = (const float*)d_in[19]; const float* fc4b = (const float*)d_in[20];
  float* out = (float*)d_out;

  // ---- workspace layout (~15 MiB) ----
  const size_t N = NPTS;
  u16* X    = (u16*)d_ws;                 // N*128 bf16
  u16* Abuf = X + N * 128;                // N*128 bf16 (fp32 S aliased at start)
  u16* T    = Abuf + N * 128;             // N*128 bf16 (bf16 H aliased at start)
  u16* IDX  = T + N * 128;                // N*40 u16
  u16* WNB  = IDX + N * 40;               // N*40 bf16
  float4* SX4g = (float4*)(WNB + N * 40); // N float4 (cell-sorted coords)
  float*  SS2g = (float*)(SX4g + N);      // N fp32
  u16*    SIDXg = (u16*)(SS2g + N);       // N u16 (sorted -> orig index)
  unsigned* binoff = (unsigned*)(SIDXg + N);   // 256
  unsigned* mm     = binoff + 256;             // 16
  float* gaabbg    = (float*)(mm + 16);        // 256*8 group AABBs
  float* S = (float*)Abuf;                // N*4 fp32 (lin_s output)
  u16* H = T;                             // N*64 bf16

  gemm_k<128, true, float, u16><<<NPTS / 64, 256, 0, stream>>>(
      x, 9, x, 9, 9, fc1W, fc1b, T, 128, 9);
  gemm_mfma_k<128, true><<<NPTS / 64, 256, 0, stream>>>(
      T, 128, T, 128, 128, fc2W, fc2b, X, 128, 128);

  for (int l = 0; l < 4; ++l) {
    init_mm_k<<<1, 64, 0, stream>>>(mm);
    gemm4_k<false, true, float><<<NPTS / 256, 256, 0, stream>>>(
        X, 128, gsW + l * 128 * 4, gsb + l * 4, S, 128, mm);
    gemm_mfma_k<64, false><<<NPTS / 64, 256, 0, stream>>>(
        X, 128, X, 128, 128, ghW + l * 128 * 64, ghb + l * 64, H, 64, 128);
    histpref_k<<<1, 1024, 0, stream>>>(S, mm, binoff);
    scatter_k<<<NPTS / 256, 256, 0, stream>>>(S, mm, binoff, SX4g, SS2g, SIDXg);
    gaabb_k<<<32, 512, 0, stream>>>(SX4g, gaabbg);
    knn_k<<<NPTS / 4, 256, 0, stream>>>(SX4g, SS2g, SIDXg, gaabbg, IDX, WNB);
    agg_k<<<NPTS / 4, 256, 0, stream>>>(H, IDX, WNB, Abuf);
    gemm_mfma_k<128, false><<<NPTS / 64, 256, 0, stream>>>(
        X, 128, Abuf, 128, 128, goW + l * 256 * 128, gob + l * 128, T, 128, 256);
    gemm_mfma_k<128, true><<<NPTS / 64, 256, 0, stream>>>(
        T, 128, T, 128, 128, d1W + l * 128 * 128, d1b + l * 128, Abuf, 128, 128);
    gemm_mfma_k<128, true><<<NPTS / 64, 256, 0, stream>>>(
        Abuf, 128, Abuf, 128, 128, d2W + l * 128 * 128, d2b + l * 128, T, 128, 128);
    gemm_mfma_k<128, true><<<NPTS / 64, 256, 0, stream>>>(
        T, 128, T, 128, 128, d3W + l * 128 * 128, d3b + l * 128, X, 128, 128);
  }

  gemm_mfma_k<128, true><<<NPTS / 64, 256, 0, stream>>>(
      X, 128, X, 128, 128, fc3W, fc3b, T, 128, 128);
  gemm4_k<false, false, float><<<NPTS / 256, 256, 0, stream>>>(
      T, 128, fc4W, fc4b, out, 128, mm);
}

// Round 4
// 1080.036 us; speedup vs baseline: 1.0848x; 1.0848x over previous
//
#include <hip/hip_runtime.h>
#include <math.h>

// Problem constants (from reference)
#define NPTS     16384
#define KNN_K    40
#define KNN_CAPW 320   // per (wave,row) survivor segment (u32 keys)

typedef unsigned short u16;
typedef __attribute__((ext_vector_type(8))) short bf16x8;
typedef __attribute__((ext_vector_type(4))) float f32x4;

// ---- bf16 (stored as ushort bits) helpers: fp32 compute, bf16 storage -----
static __device__ __forceinline__ float bf2f(unsigned short h) {
  return __uint_as_float(((unsigned)h) << 16);
}
static __device__ __forceinline__ unsigned short f2bf(float f) {
  unsigned u = __float_as_uint(f);
  unsigned r = (u + 0x7fffu + ((u >> 16) & 1u)) >> 16;   // round-nearest-even
  return (unsigned short)r;
}
static __device__ __forceinline__ float ldf(const float* p) { return *p; }
static __device__ __forceinline__ float ldf(const unsigned short* p) { return bf2f(*p); }

static __device__ __forceinline__ float rfl(float x) {   // readfirstlane -> SGPR
  return __uint_as_float(__builtin_amdgcn_readfirstlane(__float_as_uint(x)));
}
static __device__ __forceinline__ unsigned mbcnt64(unsigned long long m) {
  return __builtin_amdgcn_mbcnt_hi((unsigned)(m >> 32),
                                   __builtin_amdgcn_mbcnt_lo((unsigned)m, 0u));
}

// monotone float<->uint encoding for atomic min/max
static __device__ __forceinline__ unsigned encf(float f) {
  unsigned b = __float_as_uint(f);
  return (b & 0x80000000u) ? ~b : (b | 0x80000000u);
}
static __device__ __forceinline__ float decf(unsigned e) {
  unsigned b = (e & 0x80000000u) ? (e ^ 0x80000000u) : ~e;
  return __uint_as_float(b);
}

// ---------------------------------------------------------------------------
// Weight pre-split: all MFMA-GEMM weights converted ONCE per run into
// hi/lo bf16 tiles laid out exactly as the GEMM LDS wants them:
// per 32-k block kb: [hi: M rows x 32][lo: M rows x 32], row stride 32 u16.
// Tensor order in the output: fc2, gh(4L), go(4L), d1(4L), d2(4L), d3(4L), fc3.
// Layer tiles never cross tensor-internal layer boundaries (K%32==0).
// ---------------------------------------------------------------------------
#define WSPLIT_ELEMS 393216   // total float elems across the 7 tensors

__global__ __launch_bounds__(256, 8) void wsplit_k(
    const float* __restrict__ fc2W, const float* __restrict__ ghW,
    const float* __restrict__ goW,  const float* __restrict__ d1W,
    const float* __restrict__ d2W,  const float* __restrict__ d3W,
    const float* __restrict__ fc3W, u16* __restrict__ out)
{
  int e = blockIdx.x * 256 + threadIdx.x;
  const float* W; int base, lM;
  if (e < 16384)       { W = fc2W; base = 0;      lM = 7; }
  else if (e < 49152)  { W = ghW;  base = 16384;  lM = 6; }
  else if (e < 180224) { W = goW;  base = 49152;  lM = 7; }
  else if (e < 245760) { W = d1W;  base = 180224; lM = 7; }
  else if (e < 311296) { W = d2W;  base = 245760; lM = 7; }
  else if (e < 376832) { W = d3W;  base = 311296; lM = 7; }
  else                 { W = fc3W; base = 376832; lM = 7; }
  int li = e - base;
  int M = 1 << lM;
  int k = li >> lM, n = li & (M - 1);
  float wv = W[li];
  u16 hi = f2bf(wv);
  u16 lo = f2bf(wv - bf2f(hi));
  int kb = k >> 5, kk = k & 31;
  u16* ob = out + 2 * base + kb * (M << 6);   // kb * (2*M*32)
  ob[n * 32 + kk] = hi;
  ob[(M << 5) + n * 32 + kk] = lo;
}

// ---------------------------------------------------------------------------
// MFMA GEMM (pre-split weights): C = (relu?)(concat(A1,A2) @ W + bias).
// Wsp points at the tiled hi/lo bf16 weights; staging is pure vector copy.
// ---------------------------------------------------------------------------
template<int MCOLS, bool RELU>
__global__ __launch_bounds__(256, 2) void gemm_mfma_k(
    const u16* __restrict__ A1, int lda1,
    const u16* __restrict__ A2, int lda2, int K1,
    const u16* __restrict__ Wsp, const float* __restrict__ bias,
    u16* __restrict__ C, int ldc, int K)
{
  constexpr int CT = MCOLS / 64;
  constexpr int AST = 40;
  __shared__ u16 lds[64 * AST + 2 * MCOLS * AST];
  u16* As = lds;
  u16* Wh = lds + 64 * AST;          // Wl rows follow contiguously after MCOLS rows
  u16* Wl = Wh + MCOLS * AST;

  const int tid = threadIdx.x;
  const int lane = tid & 63;
  const int w = tid >> 6;
  const int row0 = blockIdx.x * 64;

  f32x4 acc[4][CT];
  #pragma unroll
  for (int rt = 0; rt < 4; ++rt)
    #pragma unroll
    for (int ct = 0; ct < CT; ++ct)
      acc[rt][ct] = (f32x4){0.f, 0.f, 0.f, 0.f};

  const int rbase = lane & 15;
  const int koff = (lane >> 4) * 8;

  for (int k0 = 0, kb = 0; k0 < K; k0 += 32, ++kb) {
    __syncthreads();
    {
      int r = tid >> 2, seg = tid & 3;
      int kk = k0 + seg * 8;
      const u16* src = (kk < K1) ? &A1[(size_t)(row0 + r) * lda1 + kk]
                                 : &A2[(size_t)(row0 + r) * lda2 + (kk - K1)];
      *(uint4*)&As[r * AST + seg * 8] = *(const uint4*)src;
    }
    {
      const u16* wsb = Wsp + (size_t)kb * (MCOLS << 6);
      #pragma unroll
      for (int l = tid; l < 2 * MCOLS * 4; l += 256) {
        int r = l >> 2, seg = l & 3;
        *(uint4*)&Wh[r * AST + seg * 8] = *(const uint4*)&wsb[r * 32 + seg * 8];
      }
    }
    __syncthreads();

    bf16x8 a[4];
    #pragma unroll
    for (int rt = 0; rt < 4; ++rt)
      a[rt] = *(const bf16x8*)&As[(rt * 16 + rbase) * AST + koff];
    #pragma unroll
    for (int ct = 0; ct < CT; ++ct) {
      int col = (w * CT + ct) * 16 + rbase;
      bf16x8 bh = *(const bf16x8*)&Wh[col * AST + koff];
      bf16x8 bl = *(const bf16x8*)&Wl[col * AST + koff];
      #pragma unroll
      for (int rt = 0; rt < 4; ++rt) {
        acc[rt][ct] = __builtin_amdgcn_mfma_f32_16x16x32_bf16(a[rt], bh, acc[rt][ct], 0, 0, 0);
        acc[rt][ct] = __builtin_amdgcn_mfma_f32_16x16x32_bf16(a[rt], bl, acc[rt][ct], 0, 0, 0);
      }
    }
  }

  __syncthreads();
  constexpr int CST = MCOLS + 8;
  u16* Ct = lds;
  const int rq = (lane >> 4) * 4;
  #pragma unroll
  for (int ct = 0; ct < CT; ++ct) {
    int col = (w * CT + ct) * 16 + rbase;
    float bv = bias[col];
    #pragma unroll
    for (int rt = 0; rt < 4; ++rt) {
      #pragma unroll
      for (int q = 0; q < 4; ++q) {
        float v = acc[rt][ct][q] + bv;
        if (RELU) v = fmaxf(v, 0.f);
        Ct[(rt * 16 + rq + q) * CST + col] = f2bf(v);
      }
    }
  }
  __syncthreads();
  constexpr int SEGS = MCOLS / 8;
  for (int l = tid; l < 64 * SEGS; l += 256) {
    int r = l / SEGS, sg = l % SEGS;
    *(uint4*)&C[(size_t)(row0 + r) * ldc + sg * 8] = *(const uint4*)&Ct[r * CST + sg * 8];
  }
}

// ---------------------------------------------------------------------------
// MFMA GEMM (fallback, fp32 weights converted in-kernel) — used only if the
// workspace is too small for the pre-split region.
// ---------------------------------------------------------------------------
template<int MCOLS, bool RELU>
__global__ __launch_bounds__(256, 2) void gemm_mfma_f32_k(
    const u16* __restrict__ A1, int lda1,
    const u16* __restrict__ A2, int lda2, int K1,
    const float* __restrict__ W, const float* __restrict__ bias,
    u16* __restrict__ C, int ldc, int K)
{
  constexpr int CT = MCOLS / 64;
  constexpr int AST = 40;
  __shared__ u16 lds[64 * AST + 2 * MCOLS * AST];
  u16* As = lds;
  u16* Wh = lds + 64 * AST;
  u16* Wl = Wh + MCOLS * AST;

  const int tid = threadIdx.x;
  const int lane = tid & 63;
  const int w = tid >> 6;
  const int row0 = blockIdx.x * 64;

  f32x4 acc[4][CT];
  #pragma unroll
  for (int rt = 0; rt < 4; ++rt)
    #pragma unroll
    for (int ct = 0; ct < CT; ++ct)
      acc[rt][ct] = (f32x4){0.f, 0.f, 0.f, 0.f};

  const int rbase = lane & 15;
  const int koff = (lane >> 4) * 8;

  for (int k0 = 0; k0 < K; k0 += 32) {
    __syncthreads();
    {
      int r = tid >> 2, seg = tid & 3;
      int kk = k0 + seg * 8;
      const u16* src = (kk < K1) ? &A1[(size_t)(row0 + r) * lda1 + kk]
                                 : &A2[(size_t)(row0 + r) * lda2 + (kk - K1)];
      *(uint4*)&As[r * AST + seg * 8] = *(const uint4*)src;
    }
    for (int l = tid; l < 32 * MCOLS; l += 256) {
      int n = l & (MCOLS - 1), kk = l / MCOLS;
      float wv = W[(size_t)(k0 + kk) * MCOLS + n];
      u16 h = f2bf(wv);
      Wh[n * AST + kk] = h;
      Wl[n * AST + kk] = f2bf(wv - bf2f(h));
    }
    __syncthreads();

    bf16x8 a[4];
    #pragma unroll
    for (int rt = 0; rt < 4; ++rt)
      a[rt] = *(const bf16x8*)&As[(rt * 16 + rbase) * AST + koff];
    #pragma unroll
    for (int ct = 0; ct < CT; ++ct) {
      int col = (w * CT + ct) * 16 + rbase;
      bf16x8 bh = *(const bf16x8*)&Wh[col * AST + koff];
      bf16x8 bl = *(const bf16x8*)&Wl[col * AST + koff];
      #pragma unroll
      for (int rt = 0; rt < 4; ++rt) {
        acc[rt][ct] = __builtin_amdgcn_mfma_f32_16x16x32_bf16(a[rt], bh, acc[rt][ct], 0, 0, 0);
        acc[rt][ct] = __builtin_amdgcn_mfma_f32_16x16x32_bf16(a[rt], bl, acc[rt][ct], 0, 0, 0);
      }
    }
  }

  __syncthreads();
  constexpr int CST = MCOLS + 8;
  u16* Ct = lds;
  const int rq = (lane >> 4) * 4;
  #pragma unroll
  for (int ct = 0; ct < CT; ++ct) {
    int col = (w * CT + ct) * 16 + rbase;
    float bv = bias[col];
    #pragma unroll
    for (int rt = 0; rt < 4; ++rt) {
      #pragma unroll
      for (int q = 0; q < 4; ++q) {
        float v = acc[rt][ct][q] + bv;
        if (RELU) v = fmaxf(v, 0.f);
        Ct[(rt * 16 + rq + q) * CST + col] = f2bf(v);
      }
    }
  }
  __syncthreads();
  constexpr int SEGS = MCOLS / 8;
  for (int l = tid; l < 64 * SEGS; l += 256) {
    int r = l / SEGS, sg = l % SEGS;
    *(uint4*)&C[(size_t)(row0 + r) * ldc + sg * 8] = *(const uint4*)&Ct[r * CST + sg * 8];
  }
}

// ---------------------------------------------------------------------------
// VALU GEMM (fc1 only: K=9, fp32 input)
// ---------------------------------------------------------------------------
template<int MCOLS, bool RELU, typename TIN, typename TOUT>
__global__ __launch_bounds__(256, 4) void gemm_k(
    const TIN* __restrict__ A1, int lda1,
    const TIN* __restrict__ A2, int lda2, int K1,
    const float* __restrict__ W, const float* __restrict__ bias,
    TOUT* __restrict__ C, int ldc, int K)
{
  constexpr int TCS = MCOLS / 8;
  constexpr int RPT = (64 * TCS) / 256;
  __shared__ float Asl[64][33];
  __shared__ float Ws[32][MCOLS];
  const int tid = threadIdx.x;
  const int row0 = blockIdx.x * 64;
  const int tc = tid % TCS, tr = tid / TCS;

  float acc[RPT][8];
  #pragma unroll
  for (int p = 0; p < RPT; ++p)
    #pragma unroll
    for (int q = 0; q < 8; ++q) acc[p][q] = 0.f;

  for (int k0 = 0; k0 < K; k0 += 32) {
    __syncthreads();
    for (int l = tid; l < 64 * 32; l += 256) {
      int r = l >> 5, c = l & 31, k = k0 + c;
      float v = 0.f;
      if (k < K) v = (k < K1) ? ldf(&A1[(size_t)(row0 + r) * lda1 + k])
                              : ldf(&A2[(size_t)(row0 + r) * lda2 + (k - K1)]);
      Asl[r][c] = v;
    }
    for (int l = tid; l < 32 * MCOLS; l += 256) {
      int kr = l / MCOLS, c = l % MCOLS, k = k0 + kr;
      Ws[kr][c] = (k < K) ? W[(size_t)k * MCOLS + c] : 0.f;
    }
    __syncthreads();
    #pragma unroll
    for (int kk = 0; kk < 32; ++kk) {
      float a[RPT];
      #pragma unroll
      for (int p = 0; p < RPT; ++p) a[p] = Asl[tr * RPT + p][kk];
      const float4 w0 = *(const float4*)&Ws[kk][tc * 8];
      const float4 w1 = *(const float4*)&Ws[kk][tc * 8 + 4];
      #pragma unroll
      for (int p = 0; p < RPT; ++p) {
        acc[p][0] = fmaf(a[p], w0.x, acc[p][0]);
        acc[p][1] = fmaf(a[p], w0.y, acc[p][1]);
        acc[p][2] = fmaf(a[p], w0.z, acc[p][2]);
        acc[p][3] = fmaf(a[p], w0.w, acc[p][3]);
        acc[p][4] = fmaf(a[p], w1.x, acc[p][4]);
        acc[p][5] = fmaf(a[p], w1.y, acc[p][5]);
        acc[p][6] = fmaf(a[p], w1.z, acc[p][6]);
        acc[p][7] = fmaf(a[p], w1.w, acc[p][7]);
      }
    }
  }

  const float4 b0 = *(const float4*)&bias[tc * 8];
  const float4 b1 = *(const float4*)&bias[tc * 8 + 4];
  #pragma unroll
  for (int p = 0; p < RPT; ++p) {
    int r = row0 + tr * RPT + p;
    float o[8];
    o[0] = acc[p][0] + b0.x; o[1] = acc[p][1] + b0.y;
    o[2] = acc[p][2] + b0.z; o[3] = acc[p][3] + b0.w;
    o[4] = acc[p][4] + b1.x; o[5] = acc[p][5] + b1.y;
    o[6] = acc[p][6] + b1.z; o[7] = acc[p][7] + b1.w;
    if (RELU) {
      #pragma unroll
      for (int q = 0; q < 8; ++q) o[q] = fmaxf(o[q], 0.f);
    }
    if constexpr (sizeof(TOUT) == 2) {
      unsigned p0 = (unsigned)f2bf(o[0]) | ((unsigned)f2bf(o[1]) << 16);
      unsigned p1 = (unsigned)f2bf(o[2]) | ((unsigned)f2bf(o[3]) << 16);
      unsigned p2 = (unsigned)f2bf(o[4]) | ((unsigned)f2bf(o[5]) << 16);
      unsigned p3 = (unsigned)f2bf(o[6]) | ((unsigned)f2bf(o[7]) << 16);
      uint4 pk = make_uint4(p0, p1, p2, p3);
      *(uint4*)&C[(size_t)r * ldc + tc * 8] = pk;
    } else {
      float4 o0, o1;
      o0.x = o[0]; o0.y = o[1]; o0.z = o[2]; o0.w = o[3];
      o1.x = o[4]; o1.y = o[5]; o1.z = o[6]; o1.w = o[7];
      *(float4*)&C[(size_t)r * ldc + tc * 8] = o0;
      *(float4*)&C[(size_t)r * ldc + tc * 8 + 4] = o1;
    }
  }
}

// ---------------------------------------------------------------------------
// Small-M GEMM (M = 4): lin_s (MM=true fuses per-dim min/max atomics) and fc4.
// ---------------------------------------------------------------------------
template<bool RELU, bool MM, typename TOUT>
__global__ __launch_bounds__(256, 4) void gemm4_k(
    const u16* __restrict__ A, int lda,
    const float* __restrict__ W, const float* __restrict__ bias,
    TOUT* __restrict__ C, int K, unsigned* mm)
{
  __shared__ float Wsl[128 * 4];
  __shared__ float bl[4];
  const int tid = threadIdx.x;
  for (int l = tid; l < K * 4; l += 256) Wsl[l] = W[l];
  if (tid < 4) bl[tid] = bias[tid];
  __syncthreads();
  const int row = blockIdx.x * 256 + tid;
  const u16* ap = A + (size_t)row * lda;
  float a0 = bl[0], a1 = bl[1], a2 = bl[2], a3 = bl[3];
  for (int k8 = 0; k8 < K; k8 += 8) {
    uint4 pk = *(const uint4*)&ap[k8];
    unsigned uu[4] = {pk.x, pk.y, pk.z, pk.w};
    #pragma unroll
    for (int q = 0; q < 4; ++q) {
      float flo = __uint_as_float(uu[q] << 16);
      float fhi = __uint_as_float(uu[q] & 0xFFFF0000u);
      const float* wr0 = &Wsl[(k8 + 2 * q) * 4];
      a0 = fmaf(flo, wr0[0], a0); a1 = fmaf(flo, wr0[1], a1);
      a2 = fmaf(flo, wr0[2], a2); a3 = fmaf(flo, wr0[3], a3);
      a0 = fmaf(fhi, wr0[4], a0); a1 = fmaf(fhi, wr0[5], a1);
      a2 = fmaf(fhi, wr0[6], a2); a3 = fmaf(fhi, wr0[7], a3);
    }
  }
  if (RELU) {
    a0 = fmaxf(a0, 0.f); a1 = fmaxf(a1, 0.f);
    a2 = fmaxf(a2, 0.f); a3 = fmaxf(a3, 0.f);
  }
  if constexpr (sizeof(TOUT) == 2) {
    C[(size_t)row * 4 + 0] = (TOUT)f2bf(a0);
    C[(size_t)row * 4 + 1] = (TOUT)f2bf(a1);
    C[(size_t)row * 4 + 2] = (TOUT)f2bf(a2);
    C[(size_t)row * 4 + 3] = (TOUT)f2bf(a3);
  } else {
    float4 o; o.x = a0; o.y = a1; o.z = a2; o.w = a3;
    *(float4*)&C[(size_t)row * 4] = o;
  }
  if constexpr (MM) {
    float mn0 = a0, mx0 = a0, mn1 = a1, mx1 = a1;
    float mn2 = a2, mx2 = a2, mn3 = a3, mx3 = a3;
    #pragma unroll
    for (int o = 32; o >= 1; o >>= 1) {
      mn0 = fminf(mn0, __shfl_xor(mn0, o, 64)); mx0 = fmaxf(mx0, __shfl_xor(mx0, o, 64));
      mn1 = fminf(mn1, __shfl_xor(mn1, o, 64)); mx1 = fmaxf(mx1, __shfl_xor(mx1, o, 64));
      mn2 = fminf(mn2, __shfl_xor(mn2, o, 64)); mx2 = fmaxf(mx2, __shfl_xor(mx2, o, 64));
      mn3 = fminf(mn3, __shfl_xor(mn3, o, 64)); mx3 = fmaxf(mx3, __shfl_xor(mx3, o, 64));
    }
    if ((tid & 63) == 0) {
      atomicMin(&mm[0], encf(mn0)); atomicMax(&mm[4], encf(mx0));
      atomicMin(&mm[1], encf(mn1)); atomicMax(&mm[5], encf(mx1));
      atomicMin(&mm[2], encf(mn2)); atomicMax(&mm[6], encf(mx2));
      atomicMin(&mm[3], encf(mn3)); atomicMax(&mm[7], encf(mx3));
    }
  }
}

// ---------------------------------------------------------------------------
// Cell-sort prep: init mm -> (gemm4 fills min/max) -> histpref (1 block:
// picks 2 widest dims, 16x16 hist, prefix) -> scatter -> per-group AABBs.
// ---------------------------------------------------------------------------
__global__ void init_mm_k(unsigned* mm) {
  int t = threadIdx.x;
  if (t < 4) { mm[t] = 0xFFFFFFFFu; mm[4 + t] = 0u; }
}

static __device__ __forceinline__ float dimsel(float4 p, int d) {
  return (d == 0) ? p.x : (d == 1) ? p.y : (d == 2) ? p.z : p.w;
}

__global__ __launch_bounds__(1024, 1) void histpref_k(
    const float* __restrict__ S, unsigned* __restrict__ mm,
    unsigned* __restrict__ binoff)
{
  __shared__ unsigned hist[256];
  __shared__ unsigned wsum[4];
  const int tid = threadIdx.x;
  float mn[4], rg[4];
  #pragma unroll
  for (int d = 0; d < 4; ++d) {
    mn[d] = decf(mm[d]);
    rg[d] = decf(mm[4 + d]) - mn[d];
  }
  int a = 0;
  #pragma unroll
  for (int d = 1; d < 4; ++d) if (rg[d] > rg[a]) a = d;
  int b = (a == 0) ? 1 : 0;
  #pragma unroll
  for (int d = 0; d < 4; ++d) if (d != a && rg[d] > rg[b]) b = d;
  float inva = (rg[a] > 0.f) ? (16.f / rg[a]) * 0.999999f : 0.f;
  float invb = (rg[b] > 0.f) ? (16.f / rg[b]) * 0.999999f : 0.f;
  if (tid == 0) {
    mm[8] = (unsigned)a; mm[9] = (unsigned)b;
    mm[10] = __float_as_uint(mn[a]); mm[11] = __float_as_uint(inva);
    mm[12] = __float_as_uint(mn[b]); mm[13] = __float_as_uint(invb);
  }
  if (tid < 256) hist[tid] = 0u;
  __syncthreads();
  for (int i = tid; i < NPTS; i += 1024) {
    float4 p = *(const float4*)&S[(size_t)i * 4];
    int ba = min(15, max(0, (int)((dimsel(p, a) - mn[a]) * inva)));
    int bb = min(15, max(0, (int)((dimsel(p, b) - mn[b]) * invb)));
    atomicAdd(&hist[ba * 16 + bb], 1u);
  }
  __syncthreads();
  unsigned v = 0, x = 0;
  if (tid < 256) {
    int lane = tid & 63;
    v = hist[tid]; x = v;
    #pragma unroll
    for (int o = 1; o < 64; o <<= 1) {
      unsigned t = (unsigned)__shfl_up((int)x, o, 64);
      if (lane >= o) x += t;
    }
    if (lane == 63) wsum[tid >> 6] = x;
  }
  __syncthreads();
  if (tid < 256) {
    unsigned off = 0;
    for (int k = 0; k < (tid >> 6); ++k) off += wsum[k];
    binoff[tid] = off + x - v;   // exclusive prefix
  }
}

__global__ __launch_bounds__(256, 4) void scatter_k(
    const float* __restrict__ S, const unsigned* __restrict__ mm,
    unsigned* __restrict__ binoff,
    float4* __restrict__ SX4, float* __restrict__ SS2, u16* __restrict__ SIDXs)
{
  int a = (int)mm[8], b = (int)mm[9];
  float alo = __uint_as_float(mm[10]), inva = __uint_as_float(mm[11]);
  float blo = __uint_as_float(mm[12]), invb = __uint_as_float(mm[13]);
  int i = blockIdx.x * 256 + threadIdx.x;
  float4 p = *(const float4*)&S[(size_t)i * 4];
  int ba = min(15, max(0, (int)((dimsel(p, a) - alo) * inva)));
  int bb = min(15, max(0, (int)((dimsel(p, b) - blo) * invb)));
  unsigned pos = atomicAdd(&binoff[ba * 16 + bb], 1u);
  SX4[pos] = p;
  SS2[pos] = fmaf(p.x, p.x, fmaf(p.y, p.y, fmaf(p.z, p.z, p.w * p.w)));
  SIDXs[pos] = (u16)i;
}

__global__ __launch_bounds__(512, 4) void gaabb_k(const float4* __restrict__ SX4,
                                                  float* __restrict__ gaabb) {
  int w = threadIdx.x >> 6, lane = threadIdx.x & 63;
  int g = blockIdx.x * 8 + w;
  float4 p = SX4[g * 64 + lane];
  float mnx = p.x, mny = p.y, mnz = p.z, mnw = p.w;
  float mxx = p.x, mxy = p.y, mxz = p.z, mxw = p.w;
  #pragma unroll
  for (int o = 32; o >= 1; o >>= 1) {
    mnx = fminf(mnx, __shfl_xor(mnx, o, 64)); mxx = fmaxf(mxx, __shfl_xor(mxx, o, 64));
    mny = fminf(mny, __shfl_xor(mny, o, 64)); mxy = fmaxf(mxy, __shfl_xor(mxy, o, 64));
    mnz = fminf(mnz, __shfl_xor(mnz, o, 64)); mxz = fmaxf(mxz, __shfl_xor(mxz, o, 64));
    mnw = fminf(mnw, __shfl_xor(mnw, o, 64)); mxw = fmaxf(mxw, __shfl_xor(mxw, o, 64));
  }
  if (lane == 0) {
    float4* gp = (float4*)&gaabb[g * 8];
    gp[0] = make_float4(mnx, mny, mnz, mnw);
    gp[1] = make_float4(mxx, mxy, mxz, mxw);
  }
}

// ---------------------------------------------------------------------------
// kNN v9 (exact revert of the measured-193us version): wave-cooperative,
// redundancy-free, depth-1 prefetch. See R1/R2 notes. Depth-2 prefetch was
// measured to cause scratch spills (R3: 3x HBM traffic) -- do not reintroduce
// without raising the register budget.
// ---------------------------------------------------------------------------
struct CompactRes { int cnt; unsigned thr; };

static __device__ __forceinline__ CompactRes compact_buf(unsigned* bufR, int cnt, int lane) {
  int n = min(cnt, KNN_CAPW);
  int lo = -1, hi = 0x7FFFFFFF, chi = n;
  for (int it = 0; it < 32; ++it) {
    if (chi <= 96) break;
    int mid = lo + ((hi - lo) >> 1);
    int lc = 0;
    for (int base = 0; base < n; base += 64) {
      int i = base + lane;
      bool c = (i < n) && (bufR[i] <= (unsigned)mid);
      lc += (int)__popcll(__ballot(c));
    }
    if (lc >= 40) { hi = mid; chi = lc; } else lo = mid;
  }
  unsigned thr = (unsigned)hi;
  int out = 0;
  for (int base = 0; base < n; base += 64) {
    int i = base + lane;
    unsigned key = (i < n) ? bufR[i] : 0xFFFFFFFFu;
    bool keep = (i < n) && (key <= thr);
    unsigned long long mk = __ballot(keep);
    unsigned pre = mbcnt64(mk);
    if (keep) bufR[out + (int)pre] = key;
    out += (int)__popcll(mk);
  }
  CompactRes r; r.cnt = out; r.thr = thr;
  return r;
}

__global__ __launch_bounds__(256, 4) void knn_k(
    const float4* __restrict__ SX4, const float* __restrict__ SS2,
    const u16* __restrict__ SIDXs, const float* __restrict__ gaabb,
    u16* __restrict__ idx_out, u16* __restrict__ w_out)
{
  __shared__ unsigned buf[4 * 4 * KNN_CAPW];   // 20 KB; phase-1 min2 aliases it
  __shared__ unsigned scr[4 * 128];            // 2 KB: per-row merge scratch
  __shared__ int cnts[16];                     // [wave][row]
  __shared__ unsigned thrend[16];              // [wave][row] final thr keys
  __shared__ unsigned short glist[4 * 64];     // per-wave surviving-group list
  __shared__ unsigned long long mws[4];        // group mask, 64 groups per wave
  __shared__ unsigned thrsh[4];                // per-row thr0 (uint float bits)

  const int tid = threadIdx.x;
  const int lane = tid & 63;
  const int w = tid >> 6;
  const int sp0 = blockIdx.x * 4;              // 4 rows per block, shared

  float cx[4], cy[4], cz[4], cw[4], s2r[4], thrF[4];
  int orow[4], cnt[4];
  #pragma unroll
  for (int r = 0; r < 4; ++r) {
    float4 sr = SX4[sp0 + r];
    cx[r] = rfl(-2.f * sr.x); cy[r] = rfl(-2.f * sr.y);
    cz[r] = rfl(-2.f * sr.z); cw[r] = rfl(-2.f * sr.w);
    s2r[r] = rfl(fmaf(sr.x, sr.x, fmaf(sr.y, sr.y, fmaf(sr.z, sr.z, sr.w * sr.w))));
    orow[r] = SIDXs[sp0 + r];
    cnt[r] = 0;
  }
  unsigned* bufw = &buf[w * 4 * KNN_CAPW];
  unsigned* mph = buf;   // phase-1 min2 exchange: [(r*8 + w*2+h)*64 + lane]

  // ---- phase 1 (split): wave w scans 4 of the 16 window groups ----
  {
    int gs = sp0 >> 6;
    int g0 = min(max(gs - 7, 0), 240);
    float m1[4], m2[4];
    #pragma unroll
    for (int r = 0; r < 4; ++r) { m1[r] = 3.0e38f; m2[r] = 3.0e38f; }
    #pragma unroll
    for (int gi = 0; gi < 4; ++gi) {
      int j = (g0 + w * 4 + gi) * 64 + lane;
      float4 p = SX4[j];
      float q = SS2[j];
      #pragma unroll
      for (int r = 0; r < 4; ++r) {
        float d = fmaf(cx[r], p.x, fmaf(cy[r], p.y, fmaf(cz[r], p.z,
                  fmaf(cw[r], p.w, q + s2r[r]))));
        d = fmaxf(d, 0.f);
        bool lt1 = d < m1[r];
        float nm2 = lt1 ? m1[r] : fminf(m2[r], d);
        m1[r] = fminf(m1[r], d);
        m2[r] = nm2;
      }
    }
    #pragma unroll
    for (int r = 0; r < 4; ++r) {
      mph[(r * 8 + w * 2 + 0) * 64 + lane] = __float_as_uint(m1[r]);
      mph[(r * 8 + w * 2 + 1) * 64 + lane] = __float_as_uint(m2[r]);
    }
  }
  __syncthreads();

  // ---- thr0: wave w bisects row w over the 512-value union ----
  {
    unsigned vals[8];
    #pragma unroll
    for (int s = 0; s < 8; ++s) vals[s] = mph[(w * 8 + s) * 64 + lane];
    int lo = -1, hi = 0x7F800000, chi = 512;
    for (int it = 0; it < 32; ++it) {
      if (chi <= 44 || (hi - lo) <= 1) break;
      int mid = lo + ((hi - lo) >> 1);
      int c = 0;
      #pragma unroll
      for (int s = 0; s < 8; ++s)
        c += (int)__popcll(__ballot(vals[s] <= (unsigned)mid));
      if (c >= 40) { hi = mid; chi = c; } else lo = mid;
    }
    if (lane == 0) thrsh[w] = (unsigned)hi;
  }
  __syncthreads();
  #pragma unroll
  for (int r = 0; r < 4; ++r) thrF[r] = __uint_as_float(thrsh[r]);

  // ---- group mask (split): wave w tests groups [w*64, w*64+64) ----
  {
    int g = w * 64 + lane;
    float4 mn = *(const float4*)&gaabb[g * 8];
    float4 mx = *(const float4*)&gaabb[g * 8 + 4];
    bool want = false;
    #pragma unroll
    for (int r = 0; r < 4; ++r) {
      float px = -0.5f * cx[r], py = -0.5f * cy[r];
      float pz = -0.5f * cz[r], pw = -0.5f * cw[r];
      float dx = fmaxf(fmaxf(mn.x - px, px - mx.x), 0.f);
      float dy = fmaxf(fmaxf(mn.y - py, py - mx.y), 0.f);
      float dz = fmaxf(fmaxf(mn.z - pz, pz - mx.z), 0.f);
      float dw = fmaxf(fmaxf(mn.w - pw, pw - mx.w), 0.f);
      float md = fmaf(dx, dx, fmaf(dy, dy, fmaf(dz, dz, dw * dw)));
      want |= (md <= thrF[r]);
    }
    unsigned long long bal = __ballot(want);
    if (lane == 0) mws[w] = bal;
  }
  __syncthreads();

  // ---- glist (parallel): survivors with ordinal%4 == w, via ballot-prefix --
  int ng = 0;
  {
    int ordbase = 0;
    #pragma unroll
    for (int pgi = 0; pgi < 4; ++pgi) {
      unsigned long long m = mws[pgi];
      bool want = (m >> lane) & 1ull;
      int ord = ordbase + (int)mbcnt64(m);
      if (want && ((ord & 3) == w))
        glist[w * 64 + (ord >> 2)] = (unsigned short)(pgi * 64 + lane);
      ordbase += (int)__popcll(m);
    }
    ng = (ordbase + 3 - w) >> 2;
  }

  // ---- phase 2: walk my groups with 1-group prefetch ----
  if (ng > 0) {
    int j = (int)glist[w * 64] * 64 + lane;
    float4 p = SX4[j];
    float q = SS2[j];
    unsigned sv = (unsigned)j;
    for (int i = 0; i < ng; ++i) {
      float4 pn = p; float qn = q; unsigned svn = sv;
      if (i + 1 < ng) {
        int j2 = (int)glist[w * 64 + i + 1] * 64 + lane;
        pn = SX4[j2]; qn = SS2[j2]; svn = (unsigned)j2;
      }
      #pragma unroll
      for (int r = 0; r < 4; ++r) {
        float d = fmaf(cx[r], p.x, fmaf(cy[r], p.y, fmaf(cz[r], p.z,
                  fmaf(cw[r], p.w, q + s2r[r]))));
        bool k = d <= thrF[r];
        unsigned long long mk = __ballot(k);
        if (mk) {
          int pos = cnt[r] + (int)mbcnt64(mk);
          if (k) bufw[r * KNN_CAPW + pos] =
              (__float_as_uint(fmaxf(d, 0.f)) & 0xFFFFC000u) | sv;
          cnt[r] += (int)__popcll(mk);
          if (cnt[r] >= KNN_CAPW - 64) {   // pre-group cnt <= 255 -> no overflow
            CompactRes cr = compact_buf(&bufw[r * KNN_CAPW], cnt[r], lane);
            cnt[r] = cr.cnt;
            thrF[r] = __uint_as_float((cr.thr & 0xFFFFC000u) | 0x3FFFu);
          }
        }
      }
      p = pn; q = qn; sv = svn;
    }
  }

  if (lane == 0) {
    #pragma unroll
    for (int r = 0; r < 4; ++r) {
      cnts[w * 4 + r] = cnt[r];
      thrend[w * 4 + r] = (__float_as_uint(thrF[r]) & 0xFFFFC000u) | 0x3FFFu;
    }
  }
  __syncthreads();

  // ---- merge + finalists: wave w owns row w ----
  {
    const int rr = w;
    const unsigned* seg[4];
    int c[4], off[5];
    off[0] = 0;
    #pragma unroll
    for (int s = 0; s < 4; ++s) {
      seg[s] = &buf[(s * 4 + rr) * KNN_CAPW];
      c[s] = cnts[s * 4 + rr];
      off[s + 1] = off[s] + c[s];
    }
    int mt = off[4];
    unsigned* S = &scr[rr * 128];

    if (mt > 128) {
      // hi0 = min over waves of final thr keys: valid global threshold
      unsigned hi0 = min(min(thrend[0 * 4 + rr], thrend[1 * 4 + rr]),
                         min(thrend[2 * 4 + rr], thrend[3 * 4 + rr]));
      int lc = 0;
      #pragma unroll
      for (int s = 0; s < 4; ++s)
        for (int base = 0; base < c[s]; base += 64) {
          int i = base + lane;
          bool cc = (i < c[s]) && (seg[s][i] <= hi0);
          lc += (int)__popcll(__ballot(cc));
        }
      unsigned thrm = hi0;
      if (lc > 128) {
        int lo = -1, hi = (int)hi0, chi = lc;
        for (int it = 0; it < 32; ++it) {
          if (chi <= 96) break;
          int mid = lo + ((hi - lo) >> 1);
          int lc2 = 0;
          #pragma unroll
          for (int s = 0; s < 4; ++s)
            for (int base = 0; base < c[s]; base += 64) {
              int i = base + lane;
              bool cc = (i < c[s]) && (seg[s][i] <= (unsigned)mid);
              lc2 += (int)__popcll(__ballot(cc));
            }
          if (lc2 >= 40) { hi = mid; chi = lc2; } else lo = mid;
        }
        thrm = (unsigned)hi;
      }
      int out = 0;
      #pragma unroll
      for (int s = 0; s < 4; ++s)
        for (int base = 0; base < c[s]; base += 64) {
          int i = base + lane;
          unsigned key = (i < c[s]) ? seg[s][i] : 0xFFFFFFFFu;
          bool keep = (i < c[s]) && (key <= thrm);
          unsigned long long mk = __ballot(keep);
          int pos = out + (int)mbcnt64(mk);
          if (keep && pos < 128) S[pos] = key;
          out += (int)__popcll(mk);
        }
      mt = min(out, 128);
    } else {
      #pragma unroll
      for (int s = 0; s < 4; ++s)
        for (int base = 0; base < c[s]; base += 64) {
          int i = base + lane;
          if (i < c[s]) S[off[s] + i] = seg[s][i];
        }
    }

    // exact d2 recompute + bitonic-128 sort + emit top-40
    const float fx = cx[rr], fy = cy[rr], fz = cz[rr], fw = cw[rr];
    const float s2i = s2r[rr];
    const int row = orow[rr];

    unsigned long long e0 = ~0ull, e1 = ~0ull;
    {
      int sl0 = lane * 2, sl1 = lane * 2 + 1;
      if (sl0 < mt) {
        unsigned key = S[sl0];
        unsigned sj = key & 0x3FFFu;
        float4 p = SX4[sj];
        float qj = fmaf(p.x, p.x, fmaf(p.y, p.y, fmaf(p.z, p.z, p.w * p.w)));
        float d = fmaf(fx, p.x, fmaf(fy, p.y, fmaf(fz, p.z, fmaf(fw, p.w, qj + s2i))));
        unsigned oi = (unsigned)SIDXs[sj];
        e0 = (((unsigned long long)__float_as_uint(fmaxf(d, 0.f))) << 32) | oi;
      }
      if (sl1 < mt) {
        unsigned key = S[sl1];
        unsigned sj = key & 0x3FFFu;
        float4 p = SX4[sj];
        float qj = fmaf(p.x, p.x, fmaf(p.y, p.y, fmaf(p.z, p.z, p.w * p.w)));
        float d = fmaf(fx, p.x, fmaf(fy, p.y, fmaf(fz, p.z, fmaf(fw, p.w, qj + s2i))));
        unsigned oi = (unsigned)SIDXs[sj];
        e1 = (((unsigned long long)__float_as_uint(fmaxf(d, 0.f))) << 32) | oi;
      }
    }

    #pragma unroll
    for (int k = 2; k <= 128; k <<= 1) {
      #pragma unroll
      for (int jj = k >> 1; jj >= 1; jj >>= 1) {
        bool up = (((lane * 2) & k) == 0);
        if (jj == 1) {
          unsigned long long a = (e0 < e1) ? e0 : e1;
          unsigned long long b = (e0 < e1) ? e1 : e0;
          e0 = up ? a : b; e1 = up ? b : a;
        } else {
          int lj = jj >> 1;
          bool lower = ((lane & lj) == 0);
          bool tm = (up == lower);
          unsigned long long o0 = __shfl_xor(e0, lj, 64);
          e0 = tm ? ((e0 < o0) ? e0 : o0) : ((e0 > o0) ? e0 : o0);
          unsigned long long o1 = __shfl_xor(e1, lj, 64);
          e1 = tm ? ((e1 < o1) ? e1 : o1) : ((e1 > o1) ? e1 : o1);
        }
      }
    }

    const int ob = row * KNN_K;
    if (lane < 20) {
      int v0 = lane * 2;
      idx_out[ob + v0] = (unsigned short)(e0 & 0xFFFFu);
      w_out[ob + v0] = f2bf(__expf(-10.f * __uint_as_float((unsigned)(e0 >> 32))));
      int v1 = v0 + 1;
      idx_out[ob + v1] = (unsigned short)(e1 & 0xFFFFu);
      w_out[ob + v1] = f2bf(__expf(-10.f * __uint_as_float((unsigned)(e1 >> 32))));
    }
  }
}

// ---------------------------------------------------------------------------
// Aggregation: Aout[i] = [mean_k h[idx]*w | max_k h[idx]*w]  (N x 128, bf16).
// ---------------------------------------------------------------------------
__global__ __launch_bounds__(256, 4) void agg_k(
    const unsigned short* __restrict__ h, const unsigned short* __restrict__ idxb,
    const unsigned short* __restrict__ wb, unsigned short* __restrict__ Aout)
{
  const int row = blockIdx.x * 4 + (threadIdx.x >> 6);
  const int lane = threadIdx.x & 63;
  const int base = row * KNN_K;
  float mean = 0.f, mx = -INFINITY;
  #pragma unroll 4
  for (int k = 0; k < KNN_K; ++k) {
    int j = idxb[base + k];
    float wv = bf2f(wb[base + k]);
    float m = bf2f(h[(size_t)j * 64 + lane]) * wv;
    mean += m;
    mx = fmaxf(mx, m);
  }
  Aout[(size_t)row * 128 + lane] = f2bf(mean * (1.f / 40.f));
  Aout[(size_t)row * 128 + 64 + lane] = f2bf(mx);
}

// ---------------------------------------------------------------------------
extern "C" void kernel_launch(void* const* d_in, const int* in_sizes, int n_in,
                              void* d_out, int out_size, void* d_ws, size_t ws_size,
                              hipStream_t stream)
{
  const float* x    = (const float*)d_in[0];
  const float* fc1W = (const float*)d_in[1];  const float* fc1b = (const float*)d_in[2];
  const float* fc2W = (const float*)d_in[3];  const float* fc2b = (const float*)d_in[4];
  const float* gsW  = (const float*)d_in[5];  const float* gsb  = (const float*)d_in[6];
  const float* ghW  = (const float*)d_in[7];  const float* ghb  = (const float*)d_in[8];
  const float* goW  = (const float*)d_in[9];  const float* gob  = (const float*)d_in[10];
  const float* d1W  = (const float*)d_in[11]; const float* d1b  = (const float*)d_in[12];
  const float* d2W  = (const float*)d_in[13]; const float* d2b  = (const float*)d_in[14];
  const float* d3W  = (const float*)d_in[15]; const float* d3b  = (const float*)d_in[16];
  const float* fc3W = (const float*)d_in[17]; const float* fc3b = (const float*)d_in[18];
  const float* fc4W = (const float*)d_in[19]; const float* fc4b = (const float*)d_in[20];
  float* out = (float*)d_out;

  // ---- workspace layout (~15.6 MiB + optional 1.57 MiB split weights) ----
  const size_t N = NPTS;
  u16* X    = (u16*)d_ws;                 // N*128 bf16
  u16* Abuf = X + N * 128;                // N*128 bf16 (fp32 S aliased at start)
  u16* T    = Abuf + N * 128;             // N*128 bf16 (bf16 H aliased at start)
  u16* IDX  = T + N * 128;                // N*40 u16
  u16* WNB  = IDX + N * 40;               // N*40 bf16
  float4* SX4g = (float4*)(WNB + N * 40); // N float4 (cell-sorted coords)
  float*  SS2g = (float*)(SX4g + N);      // N fp32
  u16*    SIDXg = (u16*)(SS2g + N);       // N u16 (sorted -> orig index)
  unsigned* binoff = (unsigned*)(SIDXg + N);   // 256
  unsigned* mm     = binoff + 256;             // 16
  float* gaabbg    = (float*)(mm + 16);        // 256*8 group AABBs
  float* S = (float*)Abuf;                // N*4 fp32 (lin_s output)
  u16* H = T;                             // N*64 bf16

  // pre-split weight region (after gaabb); fall back if workspace too small
  u16* WSPL = (u16*)(gaabbg + 256 * 8);
  size_t needed = (size_t)((char*)(WSPL + 2ull * WSPLIT_ELEMS) - (char*)d_ws);
  const bool PRE = ws_size >= needed;

  // split-weight u16 offsets (2x the float offsets); per-layer strides
  const size_t OF_FC2 = 0,      OF_GH = 32768, OF_GO = 98304;
  const size_t OF_D1 = 360448,  OF_D2 = 491520, OF_D3 = 622592, OF_FC3 = 753664;
  const size_t ST_GH = 16384, ST_GO = 65536, ST_D = 32768;

  if (PRE) {
    wsplit_k<<<WSPLIT_ELEMS / 256, 256, 0, stream>>>(
        fc2W, ghW, goW, d1W, d2W, d3W, fc3W, WSPL);
  }

  gemm_k<128, true, float, u16><<<NPTS / 64, 256, 0, stream>>>(
      x, 9, x, 9, 9, fc1W, fc1b, T, 128, 9);
  if (PRE)
    gemm_mfma_k<128, true><<<NPTS / 64, 256, 0, stream>>>(
        T, 128, T, 128, 128, WSPL + OF_FC2, fc2b, X, 128, 128);
  else
    gemm_mfma_f32_k<128, true><<<NPTS / 64, 256, 0, stream>>>(
        T, 128, T, 128, 128, fc2W, fc2b, X, 128, 128);

  for (int l = 0; l < 4; ++l) {
    init_mm_k<<<1, 64, 0, stream>>>(mm);
    gemm4_k<false, true, float><<<NPTS / 256, 256, 0, stream>>>(
        X, 128, gsW + l * 128 * 4, gsb + l * 4, S, 128, mm);
    if (PRE)
      gemm_mfma_k<64, false><<<NPTS / 64, 256, 0, stream>>>(
          X, 128, X, 128, 128, WSPL + OF_GH + l * ST_GH, ghb + l * 64, H, 64, 128);
    else
      gemm_mfma_f32_k<64, false><<<NPTS / 64, 256, 0, stream>>>(
          X, 128, X, 128, 128, ghW + l * 128 * 64, ghb + l * 64, H, 64, 128);
    histpref_k<<<1, 1024, 0, stream>>>(S, mm, binoff);
    scatter_k<<<NPTS / 256, 256, 0, stream>>>(S, mm, binoff, SX4g, SS2g, SIDXg);
    gaabb_k<<<32, 512, 0, stream>>>(SX4g, gaabbg);
    knn_k<<<NPTS / 4, 256, 0, stream>>>(SX4g, SS2g, SIDXg, gaabbg, IDX, WNB);
    agg_k<<<NPTS / 4, 256, 0, stream>>>(H, IDX, WNB, Abuf);
    if (PRE) {
      gemm_mfma_k<128, false><<<NPTS / 64, 256, 0, stream>>>(
          X, 128, Abuf, 128, 128, WSPL + OF_GO + l * ST_GO, gob + l * 128, T, 128, 256);
      gemm_mfma_k<128, true><<<NPTS / 64, 256, 0, stream>>>(
          T, 128, T, 128, 128, WSPL + OF_D1 + l * ST_D, d1b + l * 128, Abuf, 128, 128);
      gemm_mfma_k<128, true><<<NPTS / 64, 256, 0, stream>>>(
          Abuf, 128, Abuf, 128, 128, WSPL + OF_D2 + l * ST_D, d2b + l * 128, T, 128, 128);
      gemm_mfma_k<128, true><<<NPTS / 64, 256, 0, stream>>>(
          T, 128, T, 128, 128, WSPL + OF_D3 + l * ST_D, d3b + l * 128, X, 128, 128);
    } else {
      gemm_mfma_f32_k<128, false><<<NPTS / 64, 256, 0, stream>>>(
          X, 128, Abuf, 128, 128, goW + l * 256 * 128, gob + l * 128, T, 128, 256);
      gemm_mfma_f32_k<128, true><<<NPTS / 64, 256, 0, stream>>>(
          T, 128, T, 128, 128, d1W + l * 128 * 128, d1b + l * 128, Abuf, 128, 128);
      gemm_mfma_f32_k<128, true><<<NPTS / 64, 256, 0, stream>>>(
          Abuf, 128, Abuf, 128, 128, d2W + l * 128 * 128, d2b + l * 128, T, 128, 128);
      gemm_mfma_f32_k<128, true><<<NPTS / 64, 256, 0, stream>>>(
          T, 128, T, 128, 128, d3W + l * 128 * 128, d3b + l * 128, X, 128, 128);
    }
  }

  if (PRE)
    gemm_mfma_k<128, true><<<NPTS / 64, 256, 0, stream>>>(
        X, 128, X, 128, 128, WSPL + OF_FC3, fc3b, T, 128, 128);
  else
    gemm_mfma_f32_k<128, true><<<NPTS / 64, 256, 0, stream>>>(
        X, 128, X, 128, 128, fc3W, fc3b, T, 128, 128);
  gemm4_k<false, false, float><<<NPTS / 256, 256, 0, stream>>>(
      T, 128, fc4W, fc4b, out, 128, mm);
}

// Round 6
// 1016.420 us; speedup vs baseline: 1.1527x; 1.0626x over previous
//
#include <hip/hip_runtime.h>
#include <math.h>

// Problem constants (from reference)
#define NPTS     16384
#define KNN_K    40
#define KNN_CAPW 320   // per (wave,row) survivor segment (u32 keys)

typedef unsigned short u16;
typedef __attribute__((ext_vector_type(8))) short bf16x8;
typedef __attribute__((ext_vector_type(4))) float f32x4;

// ---- bf16 (stored as ushort bits) helpers: fp32 compute, bf16 storage -----
static __device__ __forceinline__ float bf2f(unsigned short h) {
  return __uint_as_float(((unsigned)h) << 16);
}
static __device__ __forceinline__ unsigned short f2bf(float f) {
  unsigned u = __float_as_uint(f);
  unsigned r = (u + 0x7fffu + ((u >> 16) & 1u)) >> 16;   // round-nearest-even
  return (unsigned short)r;
}
static __device__ __forceinline__ float ldf(const float* p) { return *p; }
static __device__ __forceinline__ float ldf(const unsigned short* p) { return bf2f(*p); }

static __device__ __forceinline__ float rfl(float x) {   // readfirstlane -> SGPR
  return __uint_as_float(__builtin_amdgcn_readfirstlane(__float_as_uint(x)));
}
static __device__ __forceinline__ unsigned mbcnt64(unsigned long long m) {
  return __builtin_amdgcn_mbcnt_hi((unsigned)(m >> 32),
                                   __builtin_amdgcn_mbcnt_lo((unsigned)m, 0u));
}

// monotone float<->uint encoding for atomic min/max
static __device__ __forceinline__ unsigned encf(float f) {
  unsigned b = __float_as_uint(f);
  return (b & 0x80000000u) ? ~b : (b | 0x80000000u);
}
static __device__ __forceinline__ float decf(unsigned e) {
  unsigned b = (e & 0x80000000u) ? (e ^ 0x80000000u) : ~e;
  return __uint_as_float(b);
}

// ---------------------------------------------------------------------------
// Weight pre-split: all MFMA-GEMM weights converted ONCE per run into hi/lo
// bf16 tiles in 64-COL PANELS (R5): per layer, per panel p (64 cols), per
// 32-k block kb: [hi: 64 cols x 32][lo: 64 cols x 32], row stride 32 u16.
// Panel stride = K*128 u16; layer stride = 2*K*M u16.
// Tensor order: fc2, gh(4L), go(4L), d1(4L), d2(4L), d3(4L), fc3.
// ---------------------------------------------------------------------------
#define WSPLIT_ELEMS 393216   // total float elems across the 7 tensors

__global__ __launch_bounds__(256, 8) void wsplit_k(
    const float* __restrict__ fc2W, const float* __restrict__ ghW,
    const float* __restrict__ goW,  const float* __restrict__ d1W,
    const float* __restrict__ d2W,  const float* __restrict__ d3W,
    const float* __restrict__ fc3W, u16* __restrict__ out)
{
  int e = blockIdx.x * 256 + threadIdx.x;
  const float* W; int base, M, K;   // M cols, K rows per layer
  if (e < 16384)       { W = fc2W; base = 0;      M = 128; K = 128; }
  else if (e < 49152)  { W = ghW;  base = 16384;  M = 64;  K = 128; }
  else if (e < 180224) { W = goW;  base = 49152;  M = 128; K = 256; }
  else if (e < 245760) { W = d1W;  base = 180224; M = 128; K = 128; }
  else if (e < 311296) { W = d2W;  base = 245760; M = 128; K = 128; }
  else if (e < 376832) { W = d3W;  base = 311296; M = 128; K = 128; }
  else                 { W = fc3W; base = 376832; M = 128; K = 128; }
  int li = e - base;
  float wv = W[li];
  u16 hi = f2bf(wv);
  u16 lo = f2bf(wv - bf2f(hi));
  int row = li / M;          // 0..(L*K-1), stacked layers
  int n   = li % M;
  int l   = row / K;
  int kl  = row % K;
  int p   = n >> 6, c = n & 63;
  int kb  = kl >> 5, kk = kl & 31;
  u16* ob = out + 2 * base + l * (2 * K * M) + p * (K * 128) + kb * 4096;
  ob[c * 32 + kk] = hi;
  ob[2048 + c * 32 + kk] = lo;
}

// ---------------------------------------------------------------------------
// MFMA GEMM, 64-col panel version (pre-split weights). Grid = 256 * npanels;
// panel = blockIdx>>8 (256 row-blocks per panel). 2 blocks/CU for 128-col
// GEMMs -> the per-block serial k-step latency chains overlap (R4 showed
// these dispatches were grid-starved at 1 block/CU).
// ---------------------------------------------------------------------------
template<bool RELU>
__global__ __launch_bounds__(256, 2) void gemm_mfma_k(
    const u16* __restrict__ A1, int lda1,
    const u16* __restrict__ A2, int lda2, int K1,
    const u16* __restrict__ Wsp, int pstride, const float* __restrict__ bias,
    u16* __restrict__ C, int ldc, int K)
{
  constexpr int MCOLS = 64;
  constexpr int AST = 40;
  __shared__ u16 lds[64 * AST + 2 * MCOLS * AST];   // 15 KB
  u16* As = lds;
  u16* Wh = lds + 64 * AST;
  u16* Wl = Wh + MCOLS * AST;

  const int tid = threadIdx.x;
  const int lane = tid & 63;
  const int w = tid >> 6;
  const int panel = blockIdx.x >> 8;
  const int row0 = (blockIdx.x & 255) * 64;
  Wsp += (size_t)panel * pstride;
  bias += panel * 64;
  C += panel * 64;

  f32x4 acc[4];
  #pragma unroll
  for (int rt = 0; rt < 4; ++rt)
    acc[rt] = (f32x4){0.f, 0.f, 0.f, 0.f};

  const int rbase = lane & 15;
  const int koff = (lane >> 4) * 8;

  for (int k0 = 0, kb = 0; k0 < K; k0 += 32, ++kb) {
    __syncthreads();
    {
      int r = tid >> 2, seg = tid & 3;
      int kk = k0 + seg * 8;
      const u16* src = (kk < K1) ? &A1[(size_t)(row0 + r) * lda1 + kk]
                                 : &A2[(size_t)(row0 + r) * lda2 + (kk - K1)];
      *(uint4*)&As[r * AST + seg * 8] = *(const uint4*)src;
    }
    {
      const u16* wsb = Wsp + (size_t)kb * 4096;
      #pragma unroll
      for (int l = tid; l < 2 * MCOLS * 4; l += 256) {   // 512 -> 2 iters
        int r = l >> 2, seg = l & 3;
        *(uint4*)&Wh[r * AST + seg * 8] = *(const uint4*)&wsb[r * 32 + seg * 8];
      }
    }
    __syncthreads();

    bf16x8 a[4];
    #pragma unroll
    for (int rt = 0; rt < 4; ++rt)
      a[rt] = *(const bf16x8*)&As[(rt * 16 + rbase) * AST + koff];
    {
      int col = w * 16 + rbase;
      bf16x8 bh = *(const bf16x8*)&Wh[col * AST + koff];
      bf16x8 bl = *(const bf16x8*)&Wl[col * AST + koff];
      #pragma unroll
      for (int rt = 0; rt < 4; ++rt) {
        acc[rt] = __builtin_amdgcn_mfma_f32_16x16x32_bf16(a[rt], bh, acc[rt], 0, 0, 0);
        acc[rt] = __builtin_amdgcn_mfma_f32_16x16x32_bf16(a[rt], bl, acc[rt], 0, 0, 0);
      }
    }
  }

  __syncthreads();
  constexpr int CST = MCOLS + 8;
  u16* Ct = lds;
  const int rq = (lane >> 4) * 4;
  {
    int col = w * 16 + rbase;
    float bv = bias[col];
    #pragma unroll
    for (int rt = 0; rt < 4; ++rt) {
      #pragma unroll
      for (int q = 0; q < 4; ++q) {
        float v = acc[rt][q] + bv;
        if (RELU) v = fmaxf(v, 0.f);
        Ct[(rt * 16 + rq + q) * CST + col] = f2bf(v);
      }
    }
  }
  __syncthreads();
  constexpr int SEGS = MCOLS / 8;
  for (int l = tid; l < 64 * SEGS; l += 256) {
    int r = l / SEGS, sg = l % SEGS;
    *(uint4*)&C[(size_t)(row0 + r) * ldc + sg * 8] = *(const uint4*)&Ct[r * CST + sg * 8];
  }
}

// ---------------------------------------------------------------------------
// MFMA GEMM (fallback, fp32 weights converted in-kernel) — used only if the
// workspace is too small for the pre-split region.
// ---------------------------------------------------------------------------
template<int MCOLS, bool RELU>
__global__ __launch_bounds__(256, 2) void gemm_mfma_f32_k(
    const u16* __restrict__ A1, int lda1,
    const u16* __restrict__ A2, int lda2, int K1,
    const float* __restrict__ W, const float* __restrict__ bias,
    u16* __restrict__ C, int ldc, int K)
{
  constexpr int CT = MCOLS / 64;
  constexpr int AST = 40;
  __shared__ u16 lds[64 * AST + 2 * MCOLS * AST];
  u16* As = lds;
  u16* Wh = lds + 64 * AST;
  u16* Wl = Wh + MCOLS * AST;

  const int tid = threadIdx.x;
  const int lane = tid & 63;
  const int w = tid >> 6;
  const int row0 = blockIdx.x * 64;

  f32x4 acc[4][CT];
  #pragma unroll
  for (int rt = 0; rt < 4; ++rt)
    #pragma unroll
    for (int ct = 0; ct < CT; ++ct)
      acc[rt][ct] = (f32x4){0.f, 0.f, 0.f, 0.f};

  const int rbase = lane & 15;
  const int koff = (lane >> 4) * 8;

  for (int k0 = 0; k0 < K; k0 += 32) {
    __syncthreads();
    {
      int r = tid >> 2, seg = tid & 3;
      int kk = k0 + seg * 8;
      const u16* src = (kk < K1) ? &A1[(size_t)(row0 + r) * lda1 + kk]
                                 : &A2[(size_t)(row0 + r) * lda2 + (kk - K1)];
      *(uint4*)&As[r * AST + seg * 8] = *(const uint4*)src;
    }
    for (int l = tid; l < 32 * MCOLS; l += 256) {
      int n = l & (MCOLS - 1), kk = l / MCOLS;
      float wv = W[(size_t)(k0 + kk) * MCOLS + n];
      u16 h = f2bf(wv);
      Wh[n * AST + kk] = h;
      Wl[n * AST + kk] = f2bf(wv - bf2f(h));
    }
    __syncthreads();

    bf16x8 a[4];
    #pragma unroll
    for (int rt = 0; rt < 4; ++rt)
      a[rt] = *(const bf16x8*)&As[(rt * 16 + rbase) * AST + koff];
    #pragma unroll
    for (int ct = 0; ct < CT; ++ct) {
      int col = (w * CT + ct) * 16 + rbase;
      bf16x8 bh = *(const bf16x8*)&Wh[col * AST + koff];
      bf16x8 bl = *(const bf16x8*)&Wl[col * AST + koff];
      #pragma unroll
      for (int rt = 0; rt < 4; ++rt) {
        acc[rt][ct] = __builtin_amdgcn_mfma_f32_16x16x32_bf16(a[rt], bh, acc[rt][ct], 0, 0, 0);
        acc[rt][ct] = __builtin_amdgcn_mfma_f32_16x16x32_bf16(a[rt], bl, acc[rt][ct], 0, 0, 0);
      }
    }
  }

  __syncthreads();
  constexpr int CST = MCOLS + 8;
  u16* Ct = lds;
  const int rq = (lane >> 4) * 4;
  #pragma unroll
  for (int ct = 0; ct < CT; ++ct) {
    int col = (w * CT + ct) * 16 + rbase;
    float bv = bias[col];
    #pragma unroll
    for (int rt = 0; rt < 4; ++rt) {
      #pragma unroll
      for (int q = 0; q < 4; ++q) {
        float v = acc[rt][ct][q] + bv;
        if (RELU) v = fmaxf(v, 0.f);
        Ct[(rt * 16 + rq + q) * CST + col] = f2bf(v);
      }
    }
  }
  __syncthreads();
  constexpr int SEGS = MCOLS / 8;
  for (int l = tid; l < 64 * SEGS; l += 256) {
    int r = l / SEGS, sg = l % SEGS;
    *(uint4*)&C[(size_t)(row0 + r) * ldc + sg * 8] = *(const uint4*)&Ct[r * CST + sg * 8];
  }
}

// ---------------------------------------------------------------------------
// VALU GEMM (fc1 only: K=9, fp32 input)
// ---------------------------------------------------------------------------
template<int MCOLS, bool RELU, typename TIN, typename TOUT>
__global__ __launch_bounds__(256, 4) void gemm_k(
    const TIN* __restrict__ A1, int lda1,
    const TIN* __restrict__ A2, int lda2, int K1,
    const float* __restrict__ W, const float* __restrict__ bias,
    TOUT* __restrict__ C, int ldc, int K)
{
  constexpr int TCS = MCOLS / 8;
  constexpr int RPT = (64 * TCS) / 256;
  __shared__ float Asl[64][33];
  __shared__ float Ws[32][MCOLS];
  const int tid = threadIdx.x;
  const int row0 = blockIdx.x * 64;
  const int tc = tid % TCS, tr = tid / TCS;

  float acc[RPT][8];
  #pragma unroll
  for (int p = 0; p < RPT; ++p)
    #pragma unroll
    for (int q = 0; q < 8; ++q) acc[p][q] = 0.f;

  for (int k0 = 0; k0 < K; k0 += 32) {
    __syncthreads();
    for (int l = tid; l < 64 * 32; l += 256) {
      int r = l >> 5, c = l & 31, k = k0 + c;
      float v = 0.f;
      if (k < K) v = (k < K1) ? ldf(&A1[(size_t)(row0 + r) * lda1 + k])
                              : ldf(&A2[(size_t)(row0 + r) * lda2 + (k - K1)]);
      Asl[r][c] = v;
    }
    for (int l = tid; l < 32 * MCOLS; l += 256) {
      int kr = l / MCOLS, c = l % MCOLS, k = k0 + kr;
      Ws[kr][c] = (k < K) ? W[(size_t)k * MCOLS + c] : 0.f;
    }
    __syncthreads();
    #pragma unroll
    for (int kk = 0; kk < 32; ++kk) {
      float a[RPT];
      #pragma unroll
      for (int p = 0; p < RPT; ++p) a[p] = Asl[tr * RPT + p][kk];
      const float4 w0 = *(const float4*)&Ws[kk][tc * 8];
      const float4 w1 = *(const float4*)&Ws[kk][tc * 8 + 4];
      #pragma unroll
      for (int p = 0; p < RPT; ++p) {
        acc[p][0] = fmaf(a[p], w0.x, acc[p][0]);
        acc[p][1] = fmaf(a[p], w0.y, acc[p][1]);
        acc[p][2] = fmaf(a[p], w0.z, acc[p][2]);
        acc[p][3] = fmaf(a[p], w0.w, acc[p][3]);
        acc[p][4] = fmaf(a[p], w1.x, acc[p][4]);
        acc[p][5] = fmaf(a[p], w1.y, acc[p][5]);
        acc[p][6] = fmaf(a[p], w1.z, acc[p][6]);
        acc[p][7] = fmaf(a[p], w1.w, acc[p][7]);
      }
    }
  }

  const float4 b0 = *(const float4*)&bias[tc * 8];
  const float4 b1 = *(const float4*)&bias[tc * 8 + 4];
  #pragma unroll
  for (int p = 0; p < RPT; ++p) {
    int r = row0 + tr * RPT + p;
    float o[8];
    o[0] = acc[p][0] + b0.x; o[1] = acc[p][1] + b0.y;
    o[2] = acc[p][2] + b0.z; o[3] = acc[p][3] + b0.w;
    o[4] = acc[p][4] + b1.x; o[5] = acc[p][5] + b1.y;
    o[6] = acc[p][6] + b1.z; o[7] = acc[p][7] + b1.w;
    if (RELU) {
      #pragma unroll
      for (int q = 0; q < 8; ++q) o[q] = fmaxf(o[q], 0.f);
    }
    if constexpr (sizeof(TOUT) == 2) {
      unsigned p0 = (unsigned)f2bf(o[0]) | ((unsigned)f2bf(o[1]) << 16);
      unsigned p1 = (unsigned)f2bf(o[2]) | ((unsigned)f2bf(o[3]) << 16);
      unsigned p2 = (unsigned)f2bf(o[4]) | ((unsigned)f2bf(o[5]) << 16);
      unsigned p3 = (unsigned)f2bf(o[6]) | ((unsigned)f2bf(o[7]) << 16);
      uint4 pk = make_uint4(p0, p1, p2, p3);
      *(uint4*)&C[(size_t)r * ldc + tc * 8] = pk;
    } else {
      float4 o0, o1;
      o0.x = o[0]; o0.y = o[1]; o0.z = o[2]; o0.w = o[3];
      o1.x = o[4]; o1.y = o[5]; o1.z = o[6]; o1.w = o[7];
      *(float4*)&C[(size_t)r * ldc + tc * 8] = o0;
      *(float4*)&C[(size_t)r * ldc + tc * 8 + 4] = o1;
    }
  }
}

// ---------------------------------------------------------------------------
// Small-M GEMM (M = 4): lin_s (MM=true fuses per-dim min/max atomics) and fc4.
// ---------------------------------------------------------------------------
template<bool RELU, bool MM, typename TOUT>
__global__ __launch_bounds__(256, 4) void gemm4_k(
    const u16* __restrict__ A, int lda,
    const float* __restrict__ W, const float* __restrict__ bias,
    TOUT* __restrict__ C, int K, unsigned* mm)
{
  __shared__ float Wsl[128 * 4];
  __shared__ float bl[4];
  const int tid = threadIdx.x;
  for (int l = tid; l < K * 4; l += 256) Wsl[l] = W[l];
  if (tid < 4) bl[tid] = bias[tid];
  __syncthreads();
  const int row = blockIdx.x * 256 + tid;
  const u16* ap = A + (size_t)row * lda;
  float a0 = bl[0], a1 = bl[1], a2 = bl[2], a3 = bl[3];
  for (int k8 = 0; k8 < K; k8 += 8) {
    uint4 pk = *(const uint4*)&ap[k8];
    unsigned uu[4] = {pk.x, pk.y, pk.z, pk.w};
    #pragma unroll
    for (int q = 0; q < 4; ++q) {
      float flo = __uint_as_float(uu[q] << 16);
      float fhi = __uint_as_float(uu[q] & 0xFFFF0000u);
      const float* wr0 = &Wsl[(k8 + 2 * q) * 4];
      a0 = fmaf(flo, wr0[0], a0); a1 = fmaf(flo, wr0[1], a1);
      a2 = fmaf(flo, wr0[2], a2); a3 = fmaf(flo, wr0[3], a3);
      a0 = fmaf(fhi, wr0[4], a0); a1 = fmaf(fhi, wr0[5], a1);
      a2 = fmaf(fhi, wr0[6], a2); a3 = fmaf(fhi, wr0[7], a3);
    }
  }
  if (RELU) {
    a0 = fmaxf(a0, 0.f); a1 = fmaxf(a1, 0.f);
    a2 = fmaxf(a2, 0.f); a3 = fmaxf(a3, 0.f);
  }
  if constexpr (sizeof(TOUT) == 2) {
    C[(size_t)row * 4 + 0] = (TOUT)f2bf(a0);
    C[(size_t)row * 4 + 1] = (TOUT)f2bf(a1);
    C[(size_t)row * 4 + 2] = (TOUT)f2bf(a2);
    C[(size_t)row * 4 + 3] = (TOUT)f2bf(a3);
  } else {
    float4 o; o.x = a0; o.y = a1; o.z = a2; o.w = a3;
    *(float4*)&C[(size_t)row * 4] = o;
  }
  if constexpr (MM) {
    float mn0 = a0, mx0 = a0, mn1 = a1, mx1 = a1;
    float mn2 = a2, mx2 = a2, mn3 = a3, mx3 = a3;
    #pragma unroll
    for (int o = 32; o >= 1; o >>= 1) {
      mn0 = fminf(mn0, __shfl_xor(mn0, o, 64)); mx0 = fmaxf(mx0, __shfl_xor(mx0, o, 64));
      mn1 = fminf(mn1, __shfl_xor(mn1, o, 64)); mx1 = fmaxf(mx1, __shfl_xor(mx1, o, 64));
      mn2 = fminf(mn2, __shfl_xor(mn2, o, 64)); mx2 = fmaxf(mx2, __shfl_xor(mx2, o, 64));
      mn3 = fminf(mn3, __shfl_xor(mn3, o, 64)); mx3 = fmaxf(mx3, __shfl_xor(mx3, o, 64));
    }
    if ((tid & 63) == 0) {
      atomicMin(&mm[0], encf(mn0)); atomicMax(&mm[4], encf(mx0));
      atomicMin(&mm[1], encf(mn1)); atomicMax(&mm[5], encf(mx1));
      atomicMin(&mm[2], encf(mn2)); atomicMax(&mm[6], encf(mx2));
      atomicMin(&mm[3], encf(mn3)); atomicMax(&mm[7], encf(mx3));
    }
  }
}

// ---------------------------------------------------------------------------
// Cell-sort prep: init mm -> (gemm4 fills min/max) -> histpref (1 block:
// picks 2 widest dims, 16x16 hist, prefix) -> scatter -> per-group AABBs.
// ---------------------------------------------------------------------------
__global__ void init_mm_k(unsigned* mm) {
  int t = threadIdx.x;
  if (t < 4) { mm[t] = 0xFFFFFFFFu; mm[4 + t] = 0u; }
}

static __device__ __forceinline__ float dimsel(float4 p, int d) {
  return (d == 0) ? p.x : (d == 1) ? p.y : (d == 2) ? p.z : p.w;
}

__global__ __launch_bounds__(1024, 1) void histpref_k(
    const float* __restrict__ S, unsigned* __restrict__ mm,
    unsigned* __restrict__ binoff)
{
  __shared__ unsigned hist[256];
  __shared__ unsigned wsum[4];
  const int tid = threadIdx.x;
  float mn[4], rg[4];
  #pragma unroll
  for (int d = 0; d < 4; ++d) {
    mn[d] = decf(mm[d]);
    rg[d] = decf(mm[4 + d]) - mn[d];
  }
  int a = 0;
  #pragma unroll
  for (int d = 1; d < 4; ++d) if (rg[d] > rg[a]) a = d;
  int b = (a == 0) ? 1 : 0;
  #pragma unroll
  for (int d = 0; d < 4; ++d) if (d != a && rg[d] > rg[b]) b = d;
  float inva = (rg[a] > 0.f) ? (16.f / rg[a]) * 0.999999f : 0.f;
  float invb = (rg[b] > 0.f) ? (16.f / rg[b]) * 0.999999f : 0.f;
  if (tid == 0) {
    mm[8] = (unsigned)a; mm[9] = (unsigned)b;
    mm[10] = __float_as_uint(mn[a]); mm[11] = __float_as_uint(inva);
    mm[12] = __float_as_uint(mn[b]); mm[13] = __float_as_uint(invb);
  }
  if (tid < 256) hist[tid] = 0u;
  __syncthreads();
  for (int i = tid; i < NPTS; i += 1024) {
    float4 p = *(const float4*)&S[(size_t)i * 4];
    int ba = min(15, max(0, (int)((dimsel(p, a) - mn[a]) * inva)));
    int bb = min(15, max(0, (int)((dimsel(p, b) - mn[b]) * invb)));
    atomicAdd(&hist[ba * 16 + bb], 1u);
  }
  __syncthreads();
  unsigned v = 0, x = 0;
  if (tid < 256) {
    int lane = tid & 63;
    v = hist[tid]; x = v;
    #pragma unroll
    for (int o = 1; o < 64; o <<= 1) {
      unsigned t = (unsigned)__shfl_up((int)x, o, 64);
      if (lane >= o) x += t;
    }
    if (lane == 63) wsum[tid >> 6] = x;
  }
  __syncthreads();
  if (tid < 256) {
    unsigned off = 0;
    for (int k = 0; k < (tid >> 6); ++k) off += wsum[k];
    binoff[tid] = off + x - v;   // exclusive prefix
  }
}

__global__ __launch_bounds__(256, 4) void scatter_k(
    const float* __restrict__ S, const unsigned* __restrict__ mm,
    unsigned* __restrict__ binoff,
    float4* __restrict__ SX4, float* __restrict__ SS2, u16* __restrict__ SIDXs)
{
  int a = (int)mm[8], b = (int)mm[9];
  float alo = __uint_as_float(mm[10]), inva = __uint_as_float(mm[11]);
  float blo = __uint_as_float(mm[12]), invb = __uint_as_float(mm[13]);
  int i = blockIdx.x * 256 + threadIdx.x;
  float4 p = *(const float4*)&S[(size_t)i * 4];
  int ba = min(15, max(0, (int)((dimsel(p, a) - alo) * inva)));
  int bb = min(15, max(0, (int)((dimsel(p, b) - blo) * invb)));
  unsigned pos = atomicAdd(&binoff[ba * 16 + bb], 1u);
  SX4[pos] = p;
  SS2[pos] = fmaf(p.x, p.x, fmaf(p.y, p.y, fmaf(p.z, p.z, p.w * p.w)));
  SIDXs[pos] = (u16)i;
}

__global__ __launch_bounds__(512, 4) void gaabb_k(const float4* __restrict__ SX4,
                                                  float* __restrict__ gaabb) {
  int w = threadIdx.x >> 6, lane = threadIdx.x & 63;
  int g = blockIdx.x * 8 + w;
  float4 p = SX4[g * 64 + lane];
  float mnx = p.x, mny = p.y, mnz = p.z, mnw = p.w;
  float mxx = p.x, mxy = p.y, mxz = p.z, mxw = p.w;
  #pragma unroll
  for (int o = 32; o >= 1; o >>= 1) {
    mnx = fminf(mnx, __shfl_xor(mnx, o, 64)); mxx = fmaxf(mxx, __shfl_xor(mxx, o, 64));
    mny = fminf(mny, __shfl_xor(mny, o, 64)); mxy = fmaxf(mxy, __shfl_xor(mxy, o, 64));
    mnz = fminf(mnz, __shfl_xor(mnz, o, 64)); mxz = fmaxf(mxz, __shfl_xor(mxz, o, 64));
    mnw = fminf(mnw, __shfl_xor(mnw, o, 64)); mxw = fmaxf(mxw, __shfl_xor(mxw, o, 64));
  }
  if (lane == 0) {
    float4* gp = (float4*)&gaabb[g * 8];
    gp[0] = make_float4(mnx, mny, mnz, mnw);
    gp[1] = make_float4(mxx, mxy, mxz, mxw);
  }
}

// ---------------------------------------------------------------------------
// kNN v11 = v9 + bitonic thr0 selection: the old thr0 bisect ran ~31
// iterations x 8 ballots every block; replaced by per-lane min2 (8->2,
// conservative pooled containment) + the verified bitonic-128 network on
// 32-bit keys -> EXACT pooled-40th in ~350 cycles, tighter than the bisect's
// early-break bound. Depth-1 prefetch kept (R3: depth-2 spills to scratch).
// ---------------------------------------------------------------------------
struct CompactRes { int cnt; unsigned thr; };

static __device__ __forceinline__ CompactRes compact_buf(unsigned* bufR, int cnt, int lane) {
  int n = min(cnt, KNN_CAPW);
  int lo = -1, hi = 0x7FFFFFFF, chi = n;
  for (int it = 0; it < 32; ++it) {
    if (chi <= 96) break;
    int mid = lo + ((hi - lo) >> 1);
    int lc = 0;
    for (int base = 0; base < n; base += 64) {
      int i = base + lane;
      bool c = (i < n) && (bufR[i] <= (unsigned)mid);
      lc += (int)__popcll(__ballot(c));
    }
    if (lc >= 40) { hi = mid; chi = lc; } else lo = mid;
  }
  unsigned thr = (unsigned)hi;
  int out = 0;
  for (int base = 0; base < n; base += 64) {
    int i = base + lane;
    unsigned key = (i < n) ? bufR[i] : 0xFFFFFFFFu;
    bool keep = (i < n) && (key <= thr);
    unsigned long long mk = __ballot(keep);
    unsigned pre = mbcnt64(mk);
    if (keep) bufR[out + (int)pre] = key;
    out += (int)__popcll(mk);
  }
  CompactRes r; r.cnt = out; r.thr = thr;
  return r;
}

__global__ __launch_bounds__(256, 4) void knn_k(
    const float4* __restrict__ SX4, const float* __restrict__ SS2,
    const u16* __restrict__ SIDXs, const float* __restrict__ gaabb,
    u16* __restrict__ idx_out, u16* __restrict__ w_out)
{
  __shared__ unsigned buf[4 * 4 * KNN_CAPW];   // 20 KB; phase-1 min2 aliases it
  __shared__ unsigned scr[4 * 128];            // 2 KB: per-row merge scratch
  __shared__ int cnts[16];                     // [wave][row]
  __shared__ unsigned thrend[16];              // [wave][row] final thr keys
  __shared__ unsigned short glist[4 * 64];     // per-wave surviving-group list
  __shared__ unsigned long long mws[4];        // group mask, 64 groups per wave
  __shared__ unsigned thrsh[4];                // per-row thr0 (uint float bits)

  const int tid = threadIdx.x;
  const int lane = tid & 63;
  const int w = tid >> 6;
  const int sp0 = blockIdx.x * 4;              // 4 rows per block, shared

  float cx[4], cy[4], cz[4], cw[4], s2r[4], thrF[4];
  int orow[4], cnt[4];
  #pragma unroll
  for (int r = 0; r < 4; ++r) {
    float4 sr = SX4[sp0 + r];
    cx[r] = rfl(-2.f * sr.x); cy[r] = rfl(-2.f * sr.y);
    cz[r] = rfl(-2.f * sr.z); cw[r] = rfl(-2.f * sr.w);
    s2r[r] = rfl(fmaf(sr.x, sr.x, fmaf(sr.y, sr.y, fmaf(sr.z, sr.z, sr.w * sr.w))));
    orow[r] = SIDXs[sp0 + r];
    cnt[r] = 0;
  }
  unsigned* bufw = &buf[w * 4 * KNN_CAPW];
  unsigned* mph = buf;   // phase-1 min2 exchange: [(r*8 + w*2+h)*64 + lane]

  // ---- phase 1 (split): wave w scans 4 of the 16 window groups ----
  {
    int gs = sp0 >> 6;
    int g0 = min(max(gs - 7, 0), 240);
    float m1[4], m2[4];
    #pragma unroll
    for (int r = 0; r < 4; ++r) { m1[r] = 3.0e38f; m2[r] = 3.0e38f; }
    #pragma unroll
    for (int gi = 0; gi < 4; ++gi) {
      int j = (g0 + w * 4 + gi) * 64 + lane;
      float4 p = SX4[j];
      float q = SS2[j];
      #pragma unroll
      for (int r = 0; r < 4; ++r) {
        float d = fmaf(cx[r], p.x, fmaf(cy[r], p.y, fmaf(cz[r], p.z,
                  fmaf(cw[r], p.w, q + s2r[r]))));
        d = fmaxf(d, 0.f);
        bool lt1 = d < m1[r];
        float nm2 = lt1 ? m1[r] : fminf(m2[r], d);
        m1[r] = fminf(m1[r], d);
        m2[r] = nm2;
      }
    }
    #pragma unroll
    for (int r = 0; r < 4; ++r) {
      mph[(r * 8 + w * 2 + 0) * 64 + lane] = __float_as_uint(m1[r]);
      mph[(r * 8 + w * 2 + 1) * 64 + lane] = __float_as_uint(m2[r]);
    }
  }
  __syncthreads();

  // ---- thr0: wave w selects row w's EXACT pooled-40th of the 512-value
  // union via per-lane min2 (conservative containment) + bitonic-128 ----
  {
    unsigned m1 = 0xFFFFFFFFu, m2 = 0xFFFFFFFFu;
    #pragma unroll
    for (int s = 0; s < 8; ++s) {
      unsigned v = mph[(w * 8 + s) * 64 + lane];
      bool lt = v < m1;
      unsigned nm2 = lt ? m1 : min(m2, v);
      m1 = min(m1, v);
      m2 = nm2;
    }
    unsigned e0 = m1, e1 = m2;
    #pragma unroll
    for (int k = 2; k <= 128; k <<= 1) {
      #pragma unroll
      for (int jj = k >> 1; jj >= 1; jj >>= 1) {
        bool up = (((lane * 2) & k) == 0);
        if (jj == 1) {
          unsigned a = min(e0, e1), b = max(e0, e1);
          e0 = up ? a : b; e1 = up ? b : a;
        } else {
          int lj = jj >> 1;
          bool lower = ((lane & lj) == 0);
          bool tm = (up == lower);
          unsigned o0 = (unsigned)__shfl_xor((int)e0, lj, 64);
          e0 = tm ? min(e0, o0) : max(e0, o0);
          unsigned o1 = (unsigned)__shfl_xor((int)e1, lj, 64);
          e1 = tm ? min(e1, o1) : max(e1, o1);
        }
      }
    }
    unsigned v40 = (unsigned)__shfl((int)e1, 19, 64);   // element 39 (0-based)
    if (lane == 0) thrsh[w] = v40;
  }
  __syncthreads();
  #pragma unroll
  for (int r = 0; r < 4; ++r) thrF[r] = __uint_as_float(thrsh[r]);

  // ---- group mask (split): wave w tests groups [w*64, w*64+64) ----
  {
    int g = w * 64 + lane;
    float4 mn = *(const float4*)&gaabb[g * 8];
    float4 mx = *(const float4*)&gaabb[g * 8 + 4];
    bool want = false;
    #pragma unroll
    for (int r = 0; r < 4; ++r) {
      float px = -0.5f * cx[r], py = -0.5f * cy[r];
      float pz = -0.5f * cz[r], pw = -0.5f * cw[r];
      float dx = fmaxf(fmaxf(mn.x - px, px - mx.x), 0.f);
      float dy = fmaxf(fmaxf(mn.y - py, py - mx.y), 0.f);
      float dz = fmaxf(fmaxf(mn.z - pz, pz - mx.z), 0.f);
      float dw = fmaxf(fmaxf(mn.w - pw, pw - mx.w), 0.f);
      float md = fmaf(dx, dx, fmaf(dy, dy, fmaf(dz, dz, dw * dw)));
      want |= (md <= thrF[r]);
    }
    unsigned long long bal = __ballot(want);
    if (lane == 0) mws[w] = bal;
  }
  __syncthreads();

  // ---- glist (parallel): survivors with ordinal%4 == w, via ballot-prefix --
  int ng = 0;
  {
    int ordbase = 0;
    #pragma unroll
    for (int pgi = 0; pgi < 4; ++pgi) {
      unsigned long long m = mws[pgi];
      bool want = (m >> lane) & 1ull;
      int ord = ordbase + (int)mbcnt64(m);
      if (want && ((ord & 3) == w))
        glist[w * 64 + (ord >> 2)] = (unsigned short)(pgi * 64 + lane);
      ordbase += (int)__popcll(m);
    }
    ng = (ordbase + 3 - w) >> 2;
  }

  // ---- phase 2: walk my groups with 1-group prefetch ----
  if (ng > 0) {
    int j = (int)glist[w * 64] * 64 + lane;
    float4 p = SX4[j];
    float q = SS2[j];
    unsigned sv = (unsigned)j;
    for (int i = 0; i < ng; ++i) {
      float4 pn = p; float qn = q; unsigned svn = sv;
      if (i + 1 < ng) {
        int j2 = (int)glist[w * 64 + i + 1] * 64 + lane;
        pn = SX4[j2]; qn = SS2[j2]; svn = (unsigned)j2;
      }
      #pragma unroll
      for (int r = 0; r < 4; ++r) {
        float d = fmaf(cx[r], p.x, fmaf(cy[r], p.y, fmaf(cz[r], p.z,
                  fmaf(cw[r], p.w, q + s2r[r]))));
        bool k = d <= thrF[r];
        unsigned long long mk = __ballot(k);
        if (mk) {
          int pos = cnt[r] + (int)mbcnt64(mk);
          if (k) bufw[r * KNN_CAPW + pos] =
              (__float_as_uint(fmaxf(d, 0.f)) & 0xFFFFC000u) | sv;
          cnt[r] += (int)__popcll(mk);
          if (cnt[r] >= KNN_CAPW - 64) {   // pre-group cnt <= 255 -> no overflow
            CompactRes cr = compact_buf(&bufw[r * KNN_CAPW], cnt[r], lane);
            cnt[r] = cr.cnt;
            thrF[r] = __uint_as_float((cr.thr & 0xFFFFC000u) | 0x3FFFu);
          }
        }
      }
      p = pn; q = qn; sv = svn;
    }
  }

  if (lane == 0) {
    #pragma unroll
    for (int r = 0; r < 4; ++r) {
      cnts[w * 4 + r] = cnt[r];
      thrend[w * 4 + r] = (__float_as_uint(thrF[r]) & 0xFFFFC000u) | 0x3FFFu;
    }
  }
  __syncthreads();

  // ---- merge + finalists: wave w owns row w ----
  {
    const int rr = w;
    const unsigned* seg[4];
    int c[4], off[5];
    off[0] = 0;
    #pragma unroll
    for (int s = 0; s < 4; ++s) {
      seg[s] = &buf[(s * 4 + rr) * KNN_CAPW];
      c[s] = cnts[s * 4 + rr];
      off[s + 1] = off[s] + c[s];
    }
    int mt = off[4];
    unsigned* S = &scr[rr * 128];

    if (mt > 128) {
      // hi0 = min over waves of final thr keys: valid global threshold
      unsigned hi0 = min(min(thrend[0 * 4 + rr], thrend[1 * 4 + rr]),
                         min(thrend[2 * 4 + rr], thrend[3 * 4 + rr]));
      int lc = 0;
      #pragma unroll
      for (int s = 0; s < 4; ++s)
        for (int base = 0; base < c[s]; base += 64) {
          int i = base + lane;
          bool cc = (i < c[s]) && (seg[s][i] <= hi0);
          lc += (int)__popcll(__ballot(cc));
        }
      unsigned thrm = hi0;
      if (lc > 128) {
        int lo = -1, hi = (int)hi0, chi = lc;
        for (int it = 0; it < 32; ++it) {
          if (chi <= 96) break;
          int mid = lo + ((hi - lo) >> 1);
          int lc2 = 0;
          #pragma unroll
          for (int s = 0; s < 4; ++s)
            for (int base = 0; base < c[s]; base += 64) {
              int i = base + lane;
              bool cc = (i < c[s]) && (seg[s][i] <= (unsigned)mid);
              lc2 += (int)__popcll(__ballot(cc));
            }
          if (lc2 >= 40) { hi = mid; chi = lc2; } else lo = mid;
        }
        thrm = (unsigned)hi;
      }
      int out = 0;
      #pragma unroll
      for (int s = 0; s < 4; ++s)
        for (int base = 0; base < c[s]; base += 64) {
          int i = base + lane;
          unsigned key = (i < c[s]) ? seg[s][i] : 0xFFFFFFFFu;
          bool keep = (i < c[s]) && (key <= thrm);
          unsigned long long mk = __ballot(keep);
          int pos = out + (int)mbcnt64(mk);
          if (keep && pos < 128) S[pos] = key;
          out += (int)__popcll(mk);
        }
      mt = min(out, 128);
    } else {
      #pragma unroll
      for (int s = 0; s < 4; ++s)
        for (int base = 0; base < c[s]; base += 64) {
          int i = base + lane;
          if (i < c[s]) S[off[s] + i] = seg[s][i];
        }
    }

    // exact d2 recompute + bitonic-128 sort + emit top-40
    const float fx = cx[rr], fy = cy[rr], fz = cz[rr], fw = cw[rr];
    const float s2i = s2r[rr];
    const int row = orow[rr];

    unsigned long long e0 = ~0ull, e1 = ~0ull;
    {
      int sl0 = lane * 2, sl1 = lane * 2 + 1;
      if (sl0 < mt) {
        unsigned key = S[sl0];
        unsigned sj = key & 0x3FFFu;
        float4 p = SX4[sj];
        float qj = fmaf(p.x, p.x, fmaf(p.y, p.y, fmaf(p.z, p.z, p.w * p.w)));
        float d = fmaf(fx, p.x, fmaf(fy, p.y, fmaf(fz, p.z, fmaf(fw, p.w, qj + s2i))));
        unsigned oi = (unsigned)SIDXs[sj];
        e0 = (((unsigned long long)__float_as_uint(fmaxf(d, 0.f))) << 32) | oi;
      }
      if (sl1 < mt) {
        unsigned key = S[sl1];
        unsigned sj = key & 0x3FFFu;
        float4 p = SX4[sj];
        float qj = fmaf(p.x, p.x, fmaf(p.y, p.y, fmaf(p.z, p.z, p.w * p.w)));
        float d = fmaf(fx, p.x, fmaf(fy, p.y, fmaf(fz, p.z, fmaf(fw, p.w, qj + s2i))));
        unsigned oi = (unsigned)SIDXs[sj];
        e1 = (((unsigned long long)__float_as_uint(fmaxf(d, 0.f))) << 32) | oi;
      }
    }

    #pragma unroll
    for (int k = 2; k <= 128; k <<= 1) {
      #pragma unroll
      for (int jj = k >> 1; jj >= 1; jj >>= 1) {
        bool up = (((lane * 2) & k) == 0);
        if (jj == 1) {
          unsigned long long a = (e0 < e1) ? e0 : e1;
          unsigned long long b = (e0 < e1) ? e1 : e0;
          e0 = up ? a : b; e1 = up ? b : a;
        } else {
          int lj = jj >> 1;
          bool lower = ((lane & lj) == 0);
          bool tm = (up == lower);
          unsigned long long o0 = __shfl_xor(e0, lj, 64);
          e0 = tm ? ((e0 < o0) ? e0 : o0) : ((e0 > o0) ? e0 : o0);
          unsigned long long o1 = __shfl_xor(e1, lj, 64);
          e1 = tm ? ((e1 < o1) ? e1 : o1) : ((e1 > o1) ? e1 : o1);
        }
      }
    }

    const int ob = row * KNN_K;
    if (lane < 20) {
      int v0 = lane * 2;
      idx_out[ob + v0] = (unsigned short)(e0 & 0xFFFFu);
      w_out[ob + v0] = f2bf(__expf(-10.f * __uint_as_float((unsigned)(e0 >> 32))));
      int v1 = v0 + 1;
      idx_out[ob + v1] = (unsigned short)(e1 & 0xFFFFu);
      w_out[ob + v1] = f2bf(__expf(-10.f * __uint_as_float((unsigned)(e1 >> 32))));
    }
  }
}

// ---------------------------------------------------------------------------
// Aggregation: Aout[i] = [mean_k h[idx]*w | max_k h[idx]*w]  (N x 128, bf16).
// ---------------------------------------------------------------------------
__global__ __launch_bounds__(256, 4) void agg_k(
    const unsigned short* __restrict__ h, const unsigned short* __restrict__ idxb,
    const unsigned short* __restrict__ wb, unsigned short* __restrict__ Aout)
{
  const int row = blockIdx.x * 4 + (threadIdx.x >> 6);
  const int lane = threadIdx.x & 63;
  const int base = row * KNN_K;
  float mean = 0.f, mx = -INFINITY;
  #pragma unroll 4
  for (int k = 0; k < KNN_K; ++k) {
    int j = idxb[base + k];
    float wv = bf2f(wb[base + k]);
    float m = bf2f(h[(size_t)j * 64 + lane]) * wv;
    mean += m;
    mx = fmaxf(mx, m);
  }
  Aout[(size_t)row * 128 + lane] = f2bf(mean * (1.f / 40.f));
  Aout[(size_t)row * 128 + 64 + lane] = f2bf(mx);
}

// ---------------------------------------------------------------------------
extern "C" void kernel_launch(void* const* d_in, const int* in_sizes, int n_in,
                              void* d_out, int out_size, void* d_ws, size_t ws_size,
                              hipStream_t stream)
{
  const float* x    = (const float*)d_in[0];
  const float* fc1W = (const float*)d_in[1];  const float* fc1b = (const float*)d_in[2];
  const float* fc2W = (const float*)d_in[3];  const float* fc2b = (const float*)d_in[4];
  const float* gsW  = (const float*)d_in[5];  const float* gsb  = (const float*)d_in[6];
  const float* ghW  = (const float*)d_in[7];  const float* ghb  = (const float*)d_in[8];
  const float* goW  = (const float*)d_in[9];  const float* gob  = (const float*)d_in[10];
  const float* d1W  = (const float*)d_in[11]; const float* d1b  = (const float*)d_in[12];
  const float* d2W  = (const float*)d_in[13]; const float* d2b  = (const float*)d_in[14];
  const float* d3W  = (const float*)d_in[15]; const float* d3b  = (const float*)d_in[16];
  const float* fc3W = (const float*)d_in[17]; const float* fc3b = (const float*)d_in[18];
  const float* fc4W = (const float*)d_in[19]; const float* fc4b = (const float*)d_in[20];
  float* out = (float*)d_out;

  // ---- workspace layout (~15.6 MiB + optional 1.57 MiB split weights) ----
  const size_t N = NPTS;
  u16* X    = (u16*)d_ws;                 // N*128 bf16
  u16* Abuf = X + N * 128;                // N*128 bf16 (fp32 S aliased at start)
  u16* T    = Abuf + N * 128;             // N*128 bf16 (bf16 H aliased at start)
  u16* IDX  = T + N * 128;                // N*40 u16
  u16* WNB  = IDX + N * 40;               // N*40 bf16
  float4* SX4g = (float4*)(WNB + N * 40); // N float4 (cell-sorted coords)
  float*  SS2g = (float*)(SX4g + N);      // N fp32
  u16*    SIDXg = (u16*)(SS2g + N);       // N u16 (sorted -> orig index)
  unsigned* binoff = (unsigned*)(SIDXg + N);   // 256
  unsigned* mm     = binoff + 256;             // 16
  float* gaabbg    = (float*)(mm + 16);        // 256*8 group AABBs
  float* S = (float*)Abuf;                // N*4 fp32 (lin_s output)
  u16* H = T;                             // N*64 bf16

  // pre-split weight region (after gaabb); fall back if workspace too small
  u16* WSPL = (u16*)(gaabbg + 256 * 8);
  size_t needed = (size_t)((char*)(WSPL + 2ull * WSPLIT_ELEMS) - (char*)d_ws);
  const bool PRE = ws_size >= needed;

  // split-weight u16 tensor bases; per-layer and per-panel strides
  const size_t OF_FC2 = 0,      OF_GH = 32768, OF_GO = 98304;
  const size_t OF_D1 = 360448,  OF_D2 = 491520, OF_D3 = 622592, OF_FC3 = 753664;
  const int PS_128 = 16384;   // panel stride, K=128 (K*128)
  const int PS_256 = 32768;   // panel stride, K=256
  const size_t LS_GH = 16384, LS_GO = 65536, LS_D = 32768;  // layer strides

  if (PRE) {
    wsplit_k<<<WSPLIT_ELEMS / 256, 256, 0, stream>>>(
        fc2W, ghW, goW, d1W, d2W, d3W, fc3W, WSPL);
  }

  gemm_k<128, true, float, u16><<<NPTS / 64, 256, 0, stream>>>(
      x, 9, x, 9, 9, fc1W, fc1b, T, 128, 9);
  if (PRE)
    gemm_mfma_k<true><<<512, 256, 0, stream>>>(
        T, 128, T, 128, 128, WSPL + OF_FC2, PS_128, fc2b, X, 128, 128);
  else
    gemm_mfma_f32_k<128, true><<<NPTS / 64, 256, 0, stream>>>(
        T, 128, T, 128, 128, fc2W, fc2b, X, 128, 128);

  for (int l = 0; l < 4; ++l) {
    init_mm_k<<<1, 64, 0, stream>>>(mm);
    gemm4_k<false, true, float><<<NPTS / 256, 256, 0, stream>>>(
        X, 128, gsW + l * 128 * 4, gsb + l * 4, S, 128, mm);
    if (PRE)
      gemm_mfma_k<false><<<256, 256, 0, stream>>>(
          X, 128, X, 128, 128, WSPL + OF_GH + l * LS_GH, PS_128, ghb + l * 64, H, 64, 128);
    else
      gemm_mfma_f32_k<64, false><<<NPTS / 64, 256, 0, stream>>>(
          X, 128, X, 128, 128, ghW + l * 128 * 64, ghb + l * 64, H, 64, 128);
    histpref_k<<<1, 1024, 0, stream>>>(S, mm, binoff);
    scatter_k<<<NPTS / 256, 256, 0, stream>>>(S, mm, binoff, SX4g, SS2g, SIDXg);
    gaabb_k<<<32, 512, 0, stream>>>(SX4g, gaabbg);
    knn_k<<<NPTS / 4, 256, 0, stream>>>(SX4g, SS2g, SIDXg, gaabbg, IDX, WNB);
    agg_k<<<NPTS / 4, 256, 0, stream>>>(H, IDX, WNB, Abuf);
    if (PRE) {
      gemm_mfma_k<false><<<512, 256, 0, stream>>>(
          X, 128, Abuf, 128, 128, WSPL + OF_GO + l * LS_GO, PS_256, gob + l * 128, T, 128, 256);
      gemm_mfma_k<true><<<512, 256, 0, stream>>>(
          T, 128, T, 128, 128, WSPL + OF_D1 + l * LS_D, PS_128, d1b + l * 128, Abuf, 128, 128);
      gemm_mfma_k<true><<<512, 256, 0, stream>>>(
          Abuf, 128, Abuf, 128, 128, WSPL + OF_D2 + l * LS_D, PS_128, d2b + l * 128, T, 128, 128);
      gemm_mfma_k<true><<<512, 256, 0, stream>>>(
          T, 128, T, 128, 128, WSPL + OF_D3 + l * LS_D, PS_128, d3b + l * 128, X, 128, 128);
    } else {
      gemm_mfma_f32_k<128, false><<<NPTS / 64, 256, 0, stream>>>(
          X, 128, Abuf, 128, 128, goW + l * 256 * 128, gob + l * 128, T, 128, 256);
      gemm_mfma_f32_k<128, true><<<NPTS / 64, 256, 0, stream>>>(
          T, 128, T, 128, 128, d1W + l * 128 * 128, d1b + l * 128, Abuf, 128, 128);
      gemm_mfma_f32_k<128, true><<<NPTS / 64, 256, 0, stream>>>(
          Abuf, 128, Abuf, 128, 128, d2W + l * 128 * 128, d2b + l * 128, T, 128, 128);
      gemm_mfma_f32_k<128, true><<<NPTS / 64, 256, 0, stream>>>(
          T, 128, T, 128, 128, d3W + l * 128 * 128, d3b + l * 128, X, 128, 128);
    }
  }

  if (PRE)
    gemm_mfma_k<true><<<512, 256, 0, stream>>>(
        X, 128, X, 128, 128, WSPL + OF_FC3, PS_128, fc3b, T, 128, 128);
  else
    gemm_mfma_f32_k<128, true><<<NPTS / 64, 256, 0, stream>>>(
        X, 128, X, 128, 128, fc3W, fc3b, T, 128, 128);
  gemm4_k<false, false, float><<<NPTS / 256, 256, 0, stream>>>(
      T, 128, fc4W, fc4b, out, 128, mm);
}